// Round 17
// baseline (428.319 us; speedup 1.0000x reference)
//
#include <hip/hip_runtime.h>
#include <hip/hip_fp16.h>

#define NN 50000
#define NE 1000000
#define NEP 400000
#define HD 128
#define CD 768
#define NB_SCAN 196  // ceil(NN/256)
#define FSTR 256     // feat row stride (ushorts): [z(128) | c(128)]
#define NBKT 196     // sort buckets: key = s >> 8
#define PBLK 2048    // edges per permute block
#define NPB ((2 * NEP + PBLK - 1) / PBLK)  // 391

typedef _Float16 f16x8 __attribute__((ext_vector_type(8)));
typedef _Float16 f16x2 __attribute__((ext_vector_type(2)));
typedef __fp16 hf16x2 __attribute__((ext_vector_type(2)));
typedef __attribute__((ext_vector_type(4))) float f32x4;

__device__ __forceinline__ unsigned pk2h(float a, float b) {
    hf16x2 p = __builtin_amdgcn_cvt_pkrtz(a, b);
    return __builtin_bit_cast(unsigned, p);
}
__device__ __forceinline__ ushort f2h(float x) {
    return (ushort)(pk2h(x, 0.f) & 0xffffu);
}
__device__ __forceinline__ unsigned h2mul(unsigned a, unsigned b) {
    f16x2 ha = __builtin_bit_cast(f16x2, a);
    f16x2 hb = __builtin_bit_cast(f16x2, b);
    f16x2 r = ha * hb;
    return __builtin_bit_cast(unsigned, r);
}
__device__ __forceinline__ f16x8 pack8h(float4 a0, float4 a1) {
    union { unsigned u[4]; f16x8 v; } r;
    r.u[0] = pk2h(a0.x, a0.y);
    r.u[1] = pk2h(a0.z, a0.w);
    r.u[2] = pk2h(a1.x, a1.y);
    r.u[3] = pk2h(a1.z, a1.w);
    return r.v;
}
__device__ __forceinline__ float2 h2f2(unsigned u) {
    f16x2 h = __builtin_bit_cast(f16x2, u);
    return make_float2((float)h[0], (float)h[1]);
}

// ---------------- CSR build ----------------
__global__ __launch_bounds__(256) void count_kernel(const int* __restrict__ col,
                                                    int* __restrict__ cnt) {
    int i = blockIdx.x * 256 + threadIdx.x;
    if (i < NE) atomicAdd(&cnt[col[i]], 1);
}

__global__ __launch_bounds__(256) void scan1_kernel(const int* __restrict__ cnt,
                                                    int* __restrict__ partial,
                                                    int* __restrict__ bsum,
                                                    float* __restrict__ dinv) {
    __shared__ int s[256];
    int i = blockIdx.x * 256 + threadIdx.x;
    int v = (i < NN) ? cnt[i] : 0;
    if (i < NN) dinv[i] = (v > 0) ? 1.0f / sqrtf((float)v) : 0.0f;
    s[threadIdx.x] = v;
    __syncthreads();
    for (int o = 1; o < 256; o <<= 1) {
        int t = (threadIdx.x >= o) ? s[threadIdx.x - o] : 0;
        __syncthreads();
        s[threadIdx.x] += t;
        __syncthreads();
    }
    if (i < NN) partial[i] = s[threadIdx.x] - v;
    if (threadIdx.x == 255) bsum[blockIdx.x] = s[255];
}

__global__ __launch_bounds__(256) void scan2_kernel(int* __restrict__ bsum) {
    __shared__ int s[256];
    int v = (threadIdx.x < NB_SCAN) ? bsum[threadIdx.x] : 0;
    s[threadIdx.x] = v;
    __syncthreads();
    for (int o = 1; o < 256; o <<= 1) {
        int t = (threadIdx.x >= o) ? s[threadIdx.x - o] : 0;
        __syncthreads();
        s[threadIdx.x] += t;
        __syncthreads();
    }
    if (threadIdx.x < NB_SCAN) bsum[threadIdx.x] = s[threadIdx.x] - v;
}

__global__ __launch_bounds__(256) void scan3_kernel(const int* __restrict__ partial,
                                                    const int* __restrict__ bsum,
                                                    int* __restrict__ off,
                                                    int* __restrict__ cursor) {
    int i = blockIdx.x * 256 + threadIdx.x;
    if (i < NN) {
        int o = partial[i] + bsum[blockIdx.x];
        off[i] = o;
        cursor[i] = o;
    }
}

__global__ __launch_bounds__(256) void fill_kernel(const int* __restrict__ row,
                                                   const int* __restrict__ col,
                                                   int* __restrict__ cursor,
                                                   int* __restrict__ csr_idx) {
    int e = blockIdx.x * 256 + threadIdx.x;
    if (e < NE) {
        int c = col[e], r = row[e];
        int slot = atomicAdd(&cursor[c], 1);
        csr_idx[slot] = r;
    }
}

// ---------------- edge sort by src bucket (s>>8): 3-phase, LDS cursors ----------------
__global__ __launch_bounds__(256) void ehist_kernel(const int* __restrict__ pos,
                                                    const int* __restrict__ neg,
                                                    int* __restrict__ bh,
                                                    int* __restrict__ bcnt) {
    __shared__ int h[NBKT];
    const int t = threadIdx.x;
    if (t < NBKT) h[t] = 0;
    __syncthreads();
    const int base = blockIdx.x * PBLK;
#pragma unroll
    for (int j = 0; j < 8; ++j) {
        int i = base + t + j * 256;
        if (i < 2 * NEP) {
            int s = (i < NEP) ? pos[2 * i] : neg[2 * (i - NEP)];
            atomicAdd(&h[s >> 8], 1);
        }
    }
    __syncthreads();
    if (t < NBKT) {
        bh[blockIdx.x * NBKT + t] = h[t];
        if (h[t]) atomicAdd(&bcnt[t], h[t]);
    }
}

__global__ __launch_bounds__(256) void escan_kernel(const int* __restrict__ bcnt,
                                                    int* __restrict__ base) {
    __shared__ int s[256];
    const int t = threadIdx.x;
    int v = (t < NBKT) ? bcnt[t] : 0;
    s[t] = v;
    __syncthreads();
    for (int o = 1; o < 256; o <<= 1) {
        int x = (t >= o) ? s[t - o] : 0;
        __syncthreads();
        s[t] += x;
        __syncthreads();
    }
    if (t < NBKT) base[t] = s[t] - v;
}

__global__ __launch_bounds__(256) void bscan_kernel(const int* __restrict__ bh,
                                                    int* __restrict__ obh) {
    __shared__ int p[256];
    const int b = blockIdx.x;
    const int t = threadIdx.x;
    int v0 = (2 * t < NPB) ? bh[(size_t)(2 * t) * NBKT + b] : 0;
    int v1 = (2 * t + 1 < NPB) ? bh[(size_t)(2 * t + 1) * NBKT + b] : 0;
    p[t] = v0 + v1;
    __syncthreads();
    for (int o = 1; o < 256; o <<= 1) {
        int x = (t >= o) ? p[t - o] : 0;
        __syncthreads();
        p[t] += x;
        __syncthreads();
    }
    int excl = (t > 0) ? p[t - 1] : 0;
    if (2 * t < NPB) obh[(size_t)(2 * t) * NBKT + b] = excl;
    if (2 * t + 1 < NPB) obh[(size_t)(2 * t + 1) * NBKT + b] = excl + v0;
}

__global__ __launch_bounds__(256) void epermute_kernel(const int* __restrict__ pos,
                                                       const int* __restrict__ neg,
                                                       const int* __restrict__ base,
                                                       const int* __restrict__ obh,
                                                       uint2* __restrict__ sd,
                                                       int* __restrict__ oidx) {
    __shared__ int cur[NBKT];
    const int t = threadIdx.x;
    if (t < NBKT) cur[t] = base[t] + obh[(size_t)blockIdx.x * NBKT + t];
    __syncthreads();
    const int bb = blockIdx.x * PBLK;
#pragma unroll
    for (int j = 0; j < 8; ++j) {
        int i = bb + t + j * 256;
        if (i < 2 * NEP) {
            int s, d;
            if (i < NEP) { s = pos[2 * i]; d = pos[2 * i + 1]; }
            else { s = neg[2 * (i - NEP)]; d = neg[2 * (i - NEP) + 1]; }
            int slot = atomicAdd(&cur[s >> 8], 1);
            sd[slot] = make_uint2((unsigned)s, (unsigned)d);
            oidx[slot] = i;
        }
    }
}

// ---------------- all weights -> MFMA B-fragment order, f16 (single launch) ----------------
__global__ __launch_bounds__(256) void wfrag_all_kernel(const float* __restrict__ w1,
                                                        const float* __restrict__ wc,
                                                        const float* __restrict__ w0,
                                                        const float* __restrict__ wl1,
                                                        ushort* __restrict__ w1f,
                                                        ushort* __restrict__ wcf,
                                                        ushort* __restrict__ wc0f,
                                                        ushort* __restrict__ wc1f) {
    int tid = blockIdx.x * 256 + threadIdx.x;  // [0, 20480)
    int g = tid >> 9;
    const float* w;
    ushort* wf;
    int ks;
    if (g < 8) { w = w1; wf = w1f; ks = g; }
    else if (g < 32) { w = wc; wf = wcf; ks = g - 8; }
    else if (g < 36) { w = w0; wf = wc0f; ks = g - 32; }
    else { w = wl1; wf = wc1f; ks = g - 36; }
    int nt = (tid >> 6) & 7, l = tid & 63;
    int kbase = ks * 32 + ((l >> 4) << 3);
    int colq = nt * 16 + (l & 15);
    ushort r[8];
#pragma unroll
    for (int j = 0; j < 8; ++j) r[j] = f2h(w[(size_t)(kbase + j) * HD + colq]);
    *(uint4*)&wf[(size_t)((ks * 8 + nt) * 64 + l) * 8] = *(uint4*)r;
}

// ---------------- MFMA matmul (fp32 A), double-buffered; optional row-scale (dinv) or chem epilogue ----------------
template <int KS, bool EPI, bool ROWSCALE>
__global__ __launch_bounds__(256) void feat_mfma_kernel(const float* __restrict__ A,
                                                        const ushort* __restrict__ wf,
                                                        const float* __restrict__ bias,
                                                        const float* __restrict__ mask,
                                                        const float* __restrict__ rscale,
                                                        ushort* __restrict__ out,
                                                        int ostride, int ooff) {
    __shared__ float At[2][64][36];
    const int t = threadIdx.x;
    const int w = t >> 6, lane = t & 63;
    const int rowBase = blockIdx.x * 64;
    const int nt0 = w * 2;
    const int K = KS * 32;

    const int sr0 = t >> 3, sr1 = 32 + (t >> 3), sc4 = (t & 7) * 4;
    const int g0 = rowBase + sr0, g1 = rowBase + sr1;

    float4 p0 = make_float4(0.f, 0.f, 0.f, 0.f), p1 = p0;
    if (g0 < NN) p0 = *(const float4*)&A[(size_t)g0 * K + sc4];
    if (g1 < NN) p1 = *(const float4*)&A[(size_t)g1 * K + sc4];

    f32x4 acc[4][2] = {};

    for (int ks = 0; ks < KS; ++ks) {
        const int b = ks & 1;
        *(float4*)&At[b][sr0][sc4] = p0;
        *(float4*)&At[b][sr1][sc4] = p1;
        __syncthreads();
        if (ks + 1 < KS) {
            p0 = make_float4(0.f, 0.f, 0.f, 0.f); p1 = p0;
            if (g0 < NN) p0 = *(const float4*)&A[(size_t)g0 * K + (ks + 1) * 32 + sc4];
            if (g1 < NN) p1 = *(const float4*)&A[(size_t)g1 * K + (ks + 1) * 32 + sc4];
        }
        f16x8 bf0 = ((const f16x8*)wf)[(ks * 8 + nt0) * 64 + lane];
        f16x8 bf1 = ((const f16x8*)wf)[(ks * 8 + nt0 + 1) * 64 + lane];
#pragma unroll
        for (int mt = 0; mt < 4; ++mt) {
            int row = mt * 16 + (lane & 15);
            float4 a0 = *(const float4*)&At[b][row][(lane >> 4) * 8];
            float4 a1 = *(const float4*)&At[b][row][(lane >> 4) * 8 + 4];
            f16x8 af = pack8h(a0, a1);
            acc[mt][0] = __builtin_amdgcn_mfma_f32_16x16x32_f16(af, bf0, acc[mt][0], 0, 0, 0);
            acc[mt][1] = __builtin_amdgcn_mfma_f32_16x16x32_f16(af, bf1, acc[mt][1], 0, 0, 0);
        }
    }

    const int c0 = lane & 15, rq = lane >> 4;
    float bb0 = EPI ? bias[nt0 * 16 + c0] : 0.f;
    float bb1 = EPI ? bias[nt0 * 16 + 16 + c0] : 0.f;
#pragma unroll
    for (int mt = 0; mt < 4; ++mt) {
#pragma unroll
        for (int reg = 0; reg < 4; ++reg) {
            int grow = rowBase + mt * 16 + rq * 4 + reg;
            if (grow < NN) {
                float v0 = acc[mt][0][reg], v1 = acc[mt][1][reg];
                if (EPI) {
                    float m = mask[grow];
                    v0 = fmaxf(v0 + bb0, 0.f) * m;
                    v1 = fmaxf(v1 + bb1, 0.f) * m;
                }
                if (ROWSCALE) {
                    float rs = rscale[grow];
                    v0 *= rs;
                    v1 *= rs;
                }
                out[(size_t)grow * ostride + ooff + nt0 * 16 + c0] = f2h(v0);
                out[(size_t)grow * ostride + ooff + nt0 * 16 + 16 + c0] = f2h(v1);
            }
        }
    }
}

// ---------------- MFMA matmul (f16 A, K=128), double-buffered, row-scaled out ----------------
__global__ __launch_bounds__(256) void feat_mfma_f16a_kernel(const ushort* __restrict__ A,
                                                             const ushort* __restrict__ wf,
                                                             const float* __restrict__ rscale,
                                                             ushort* __restrict__ out) {
    __shared__ ushort At[2][64][40];
    const int t = threadIdx.x;
    const int w = t >> 6, lane = t & 63;
    const int rowBase = blockIdx.x * 64;
    const int nt0 = w * 2;

    const int sr = t >> 2, sc = (t & 3) * 8;
    const int g = rowBase + sr;

    uint4 p = make_uint4(0, 0, 0, 0);
    if (g < NN) p = *(const uint4*)&A[(size_t)g * HD + sc];

    f32x4 acc[4][2] = {};

    for (int ks = 0; ks < 4; ++ks) {
        const int b = ks & 1;
        *(uint4*)&At[b][sr][sc] = p;
        __syncthreads();
        if (ks + 1 < 4) {
            p = make_uint4(0, 0, 0, 0);
            if (g < NN) p = *(const uint4*)&A[(size_t)g * HD + (ks + 1) * 32 + sc];
        }
        f16x8 bf0 = ((const f16x8*)wf)[(ks * 8 + nt0) * 64 + lane];
        f16x8 bf1 = ((const f16x8*)wf)[(ks * 8 + nt0 + 1) * 64 + lane];
#pragma unroll
        for (int mt = 0; mt < 4; ++mt) {
            int row = mt * 16 + (lane & 15);
            f16x8 af = *(const f16x8*)&At[b][row][(lane >> 4) * 8];
            acc[mt][0] = __builtin_amdgcn_mfma_f32_16x16x32_f16(af, bf0, acc[mt][0], 0, 0, 0);
            acc[mt][1] = __builtin_amdgcn_mfma_f32_16x16x32_f16(af, bf1, acc[mt][1], 0, 0, 0);
        }
    }

    const int c0 = lane & 15, rq = lane >> 4;
#pragma unroll
    for (int mt = 0; mt < 4; ++mt) {
#pragma unroll
        for (int reg = 0; reg < 4; ++reg) {
            int grow = rowBase + mt * 16 + rq * 4 + reg;
            if (grow < NN) {
                float rs = rscale[grow];
                out[(size_t)grow * HD + nt0 * 16 + c0] = f2h(acc[mt][0][reg] * rs);
                out[(size_t)grow * HD + nt0 * 16 + 16 + c0] = f2h(acc[mt][1][reg] * rs);
            }
        }
    }
}

// ---------------- CSR pull aggregation (h pre-scaled by dinv[src]): 2 rows/wave ----------------
__global__ __launch_bounds__(256) void gather_kernel(const int* __restrict__ off,
                                                     const int* __restrict__ cnt,
                                                     const int* __restrict__ csr_idx,
                                                     const float* __restrict__ dinv,
                                                     const ushort* __restrict__ h,
                                                     const float* __restrict__ bias,
                                                     ushort* __restrict__ zb,
                                                     int ostride) {
    int v = blockIdx.x * 4 + (threadIdx.x >> 6);
    if (v >= NN) return;
    const int lane = threadIdx.x & 63;
    const int half = lane >> 5, sl = lane & 31;
    const int s = off[v];
    const int e = s + cnt[v];
    float4 acc = make_float4(0.f, 0.f, 0.f, 0.f);
    int b = s;
    for (; b + 7 < e; b += 8) {
        int i0 = b + half, i1 = b + 2 + half, i2 = b + 4 + half, i3 = b + 6 + half;
        int r0 = csr_idx[i0], r1 = csr_idx[i1], r2 = csr_idx[i2], r3 = csr_idx[i3];
        uint2 u0 = *(const uint2*)&h[(size_t)r0 * HD + sl * 4];
        uint2 u1 = *(const uint2*)&h[(size_t)r1 * HD + sl * 4];
        uint2 u2 = *(const uint2*)&h[(size_t)r2 * HD + sl * 4];
        uint2 u3 = *(const uint2*)&h[(size_t)r3 * HD + sl * 4];
        float2 a0 = h2f2(u0.x), c0 = h2f2(u0.y);
        float2 a1 = h2f2(u1.x), c1 = h2f2(u1.y);
        float2 a2 = h2f2(u2.x), c2 = h2f2(u2.y);
        float2 a3 = h2f2(u3.x), c3 = h2f2(u3.y);
        acc.x += a0.x + a1.x + a2.x + a3.x;
        acc.y += a0.y + a1.y + a2.y + a3.y;
        acc.z += c0.x + c1.x + c2.x + c3.x;
        acc.w += c0.y + c1.y + c2.y + c3.y;
    }
    for (; b < e; b += 2) {
        int i = b + half;
        if (i < e) {
            int r = csr_idx[i];
            uint2 u = *(const uint2*)&h[(size_t)r * HD + sl * 4];
            float2 a = h2f2(u.x), c = h2f2(u.y);
            acc.x += a.x; acc.y += a.y;
            acc.z += c.x; acc.w += c.y;
        }
    }
    acc.x += __shfl_xor(acc.x, 32);
    acc.y += __shfl_xor(acc.y, 32);
    acc.z += __shfl_xor(acc.z, 32);
    acc.w += __shfl_xor(acc.w, 32);
    if (half == 0) {
        float dv = dinv[v];
        float4 bb = *(const float4*)&bias[sl * 4];
        float o0 = fmaxf(fmaf(acc.x, dv, bb.x), 0.f);
        float o1 = fmaxf(fmaf(acc.y, dv, bb.y), 0.f);
        float o2 = fmaxf(fmaf(acc.z, dv, bb.z), 0.f);
        float o3 = fmaxf(fmaf(acc.w, dv, bb.w), 0.f);
        uint2 pk;
        pk.x = pk2h(o0, o1);
        pk.y = pk2h(o2, o3);
        *(uint2*)&zb[(size_t)v * ostride + sl * 4] = pk;
    }
}

// ---------------- decoder: f16 MFMA, half-tile staging (16KB LDS, high occupancy) ----------------
// block = 64 edges, 4 waves; two halves of 32 edges each: stage -> MFMA -> stage -> MFMA.
__global__ __launch_bounds__(256, 8) void decode_mfma_kernel(const uint2* __restrict__ sedges,
                                                             const int* __restrict__ soidx,
                                                             const ushort* __restrict__ feat,
                                                             const ushort* __restrict__ w1f,
                                                             const float* __restrict__ b1,
                                                             const float* __restrict__ w2,
                                                             const float* __restrict__ b2,
                                                             float* __restrict__ out) {
    __shared__ ushort Flds[8 * 2 * 64 * 8];  // 16 KB: [ks][mtl][64][8]; reused for partials
    const int t = threadIdx.x;
    const int w = t >> 6, lane = t & 63;

    // bijective XCD-chunked swizzle (m204)
    const int nwg = gridDim.x;
    const int orig = blockIdx.x;
    const int q = nwg >> 3, r = nwg & 7;
    const int xcd = orig & 7, k = orig >> 3;
    const int wgid = (xcd < r ? xcd * (q + 1) : r * (q + 1) + (xcd - r) * q) + k;
    const int ebase = wgid * 64;

    const int seg = t & 31, eslot = t >> 5;
    f32x4 acc[4][2] = {};
    const int nt0 = w * 2;

#pragma unroll
    for (int hf = 0; hf < 2; ++hf) {
        // stage 32 edges (hf*32 .. hf*32+31)
        uint2 sdv[4];
#pragma unroll
        for (int j = 0; j < 4; ++j) sdv[j] = sedges[ebase + hf * 32 + j * 8 + eslot];
        __builtin_amdgcn_sched_barrier(0);
        uint4 av[4], bv[4];
#pragma unroll
        for (int j = 0; j < 4; ++j) {
            av[j] = *(const uint4*)&feat[(size_t)sdv[j].x * FSTR + seg * 8];
            bv[j] = *(const uint4*)&feat[(size_t)sdv[j].y * FSTR + seg * 8];
        }
        __builtin_amdgcn_sched_barrier(0);
#pragma unroll
        for (int j = 0; j < 4; ++j) {
            int el = j * 8 + eslot;  // local edge 0..31
            uint4 res;
            res.x = h2mul(av[j].x, bv[j].x);
            res.y = h2mul(av[j].y, bv[j].y);
            res.z = h2mul(av[j].z, bv[j].z);
            res.w = h2mul(av[j].w, bv[j].w);
            int ks = seg >> 2;
            int mtl = el >> 4;
            int fl = (el & 15) | ((seg & 3) << 4);
            int swz = (seg & 3) | ((ks & 1) << 2);
            ((uint4*)Flds)[(ks * 2 + mtl) * 64 + (fl ^ swz)] = res;
        }
        __syncthreads();

#pragma unroll
        for (int ks = 0; ks < 8; ++ks) {
            f16x8 bf0 = ((const f16x8*)w1f)[(ks * 8 + nt0) * 64 + lane];
            f16x8 bf1 = ((const f16x8*)w1f)[(ks * 8 + nt0 + 1) * 64 + lane];
            const int rswz = ((lane >> 4) & 3) | ((ks & 1) << 2);
#pragma unroll
            for (int mtl = 0; mtl < 2; ++mtl) {
                f16x8 af = ((const f16x8*)Flds)[(ks * 2 + mtl) * 64 + (lane ^ rswz)];
                int mt = hf * 2 + mtl;
                acc[mt][0] = __builtin_amdgcn_mfma_f32_16x16x32_f16(af, bf0, acc[mt][0], 0, 0, 0);
                acc[mt][1] = __builtin_amdgcn_mfma_f32_16x16x32_f16(af, bf1, acc[mt][1], 0, 0, 0);
            }
        }
        __syncthreads();  // all waves done reading this half before restaging / reuse
    }

    float* partf = (float*)Flds;  // [4][64] = 1 KB
    const int c0 = lane & 15, rq = lane >> 4;
    float b1v0 = b1[nt0 * 16 + c0], b1v1 = b1[nt0 * 16 + 16 + c0];
    float w2v0 = w2[nt0 * 16 + c0], w2v1 = w2[nt0 * 16 + 16 + c0];
#pragma unroll
    for (int mt = 0; mt < 4; ++mt) {
#pragma unroll
        for (int reg = 0; reg < 4; ++reg) {
            float h0 = fmaxf(acc[mt][0][reg] + b1v0, 0.f);
            float h1 = fmaxf(acc[mt][1][reg] + b1v1, 0.f);
            float p = fmaf(h0, w2v0, h1 * w2v1);
            p += __shfl_xor(p, 1);
            p += __shfl_xor(p, 2);
            p += __shfl_xor(p, 4);
            p += __shfl_xor(p, 8);
            if (c0 == 0) partf[w * 64 + mt * 16 + rq * 4 + reg] = p;
        }
    }
    __syncthreads();
    if (t < 64) {
        out[soidx[ebase + t]] = partf[t] + partf[64 + t] + partf[128 + t] + partf[192 + t] + b2[0];
    }
}

extern "C" void kernel_launch(void* const* d_in, const int* in_sizes, int n_in,
                              void* d_out, int out_size, void* d_ws, size_t ws_size,
                              hipStream_t stream) {
    const int* edge_index = (const int*)d_in[0];
    const float* chemistry = (const float*)d_in[1];
    const int* pos_edge = (const int*)d_in[2];
    const int* neg_edge = (const int*)d_in[3];
    const float* smiles_mask = (const float*)d_in[4];
    const float* node_emb = (const float*)d_in[5];
    const float* conv_w = (const float*)d_in[6];
    const float* conv_b = (const float*)d_in[7];
    const float* chem_w = (const float*)d_in[8];
    const float* chem_b = (const float*)d_in[9];
    const float* dec_w1 = (const float*)d_in[10];
    const float* dec_b1 = (const float*)d_in[11];
    const float* dec_w2 = (const float*)d_in[12];
    const float* dec_b2 = (const float*)d_in[13];
    float* out = (float*)d_out;

    char* ws = (char*)d_ws;
    int* cnt = (int*)(ws + 0);               // 200000 B
    int* bcnt = (int*)(ws + 204800);         // 784 B (memset covers [0, 205824))
    float* dinv = (float*)(ws + 208896);
    int* partial = (int*)(ws + 409600);
    int* off = (int*)(ws + 614400);
    int* cursor = (int*)(ws + 819200);
    int* bsum = (int*)(ws + 1024000);
    int* bbase = (int*)(ws + 1026048);
    int* csr_idx = (int*)(ws + 1048576);     // 4 MB
    ushort* bufZh = (ushort*)(ws + 9437184); // 12.8 MB (f16 z, layer-0 out)
    int* bh = (int*)(ws + 22237184);         // 307 KB
    int* obh = (int*)(ws + 22657184);        // 307 KB
    ushort* hb = (ushort*)(ws + 35037184);   // 12.8 MB (h; reused for sorted edges)
    ushort* feat = (ushort*)(ws + 47837184); // 25.6 MB  [z | c] interleaved
    ushort* w1f = (ushort*)(ws + 73437184);  // 64 KB
    ushort* wcf = (ushort*)(ws + 73502720);  // 192 KB
    ushort* wc0f = (ushort*)(ws + 73699328); // 32 KB
    ushort* wc1f = (ushort*)(ws + 73732096); // 32 KB
    uint2* sort_sd = (uint2*)(ws + 35037184);   // 6.4 MB (hb region, after gather1)
    int* sort_oidx = (int*)(ws + 41437184);     // 3.2 MB

    const int* e_row = edge_index;
    const int* e_col = edge_index + NE;

    // ---- CSR build + weight fragment pack ----
    hipMemsetAsync(ws, 0, 205824, stream);  // cnt + bcnt
    count_kernel<<<(NE + 255) / 256, 256, 0, stream>>>(e_col, cnt);
    scan1_kernel<<<NB_SCAN, 256, 0, stream>>>(cnt, partial, bsum, dinv);
    scan2_kernel<<<1, 256, 0, stream>>>(bsum);
    scan3_kernel<<<NB_SCAN, 256, 0, stream>>>(partial, bsum, off, cursor);
    fill_kernel<<<(NE + 255) / 256, 256, 0, stream>>>(e_row, e_col, cursor, csr_idx);
    wfrag_all_kernel<<<80, 256, 0, stream>>>(dec_w1, chem_w, conv_w, conv_w + HD * HD,
                                             w1f, wcf, wc0f, wc1f);

    const int mmGrid = (NN + 63) / 64;
    const int gaGrid = (NN + 3) / 4;

    // layer 0: h' = (node_emb @ W0) * dinv[row]  (MFMA), aggregate -> f16 z (bufZh)
    feat_mfma_kernel<4, false, true><<<mmGrid, 256, 0, stream>>>(node_emb, wc0f, nullptr, nullptr, dinv, hb, HD, 0);
    gather_kernel<<<gaGrid, 256, 0, stream>>>(off, cnt, csr_idx, dinv, hb, conv_b, bufZh, HD);

    // layer 1: h' = (z @ W1) * dinv[row]  (f16-A MFMA), aggregate -> f16 z into feat[:,0:128]
    feat_mfma_f16a_kernel<<<mmGrid, 256, 0, stream>>>(bufZh, wc1f, dinv, hb);
    gather_kernel<<<gaGrid, 256, 0, stream>>>(off, cnt, csr_idx, dinv, hb, conv_b + HD, feat, FSTR);

    // ---- edge sort (scratch in freed regions; hb dead after gather1) ----
    ehist_kernel<<<NPB, 256, 0, stream>>>(pos_edge, neg_edge, bh, bcnt);
    escan_kernel<<<1, 256, 0, stream>>>(bcnt, bbase);
    bscan_kernel<<<NBKT, 256, 0, stream>>>(bh, obh);
    epermute_kernel<<<NPB, 256, 0, stream>>>(pos_edge, neg_edge, bbase, obh, sort_sd, sort_oidx);

    // chemistry features -> feat[:,128:256]
    feat_mfma_kernel<24, true, false><<<mmGrid, 256, 0, stream>>>(chemistry, wcf, chem_b, smiles_mask, nullptr, feat, FSTR, HD);

    // decode (pos+neg together, sorted order, scatter by original index)
    decode_mfma_kernel<<<2 * NEP / 64, 256, 0, stream>>>(sort_sd, sort_oidx, feat, w1f,
                                                         dec_b1, dec_w2, dec_b2, out);
}

// Round 18
// 413.578 us; speedup vs baseline: 1.0356x; 1.0356x over previous
//
#include <hip/hip_runtime.h>
#include <hip/hip_fp16.h>

#define NN 50000
#define NE 1000000
#define NEP 400000
#define HD 128
#define CD 768
#define NB_SCAN 196  // ceil(NN/256)
#define FSTR 256     // feat row stride (ushorts): [z(128) | c(128)]
#define NBKT 196     // sort buckets: key = s >> 8
#define PBLK 2048    // edges per permute block
#define NPB ((2 * NEP + PBLK - 1) / PBLK)  // 391

typedef _Float16 f16x8 __attribute__((ext_vector_type(8)));
typedef _Float16 f16x2 __attribute__((ext_vector_type(2)));
typedef __fp16 hf16x2 __attribute__((ext_vector_type(2)));
typedef __attribute__((ext_vector_type(4))) float f32x4;

__device__ __forceinline__ unsigned pk2h(float a, float b) {
    hf16x2 p = __builtin_amdgcn_cvt_pkrtz(a, b);
    return __builtin_bit_cast(unsigned, p);
}
__device__ __forceinline__ ushort f2h(float x) {
    return (ushort)(pk2h(x, 0.f) & 0xffffu);
}
__device__ __forceinline__ unsigned h2mul(unsigned a, unsigned b) {
    f16x2 ha = __builtin_bit_cast(f16x2, a);
    f16x2 hb = __builtin_bit_cast(f16x2, b);
    f16x2 r = ha * hb;
    return __builtin_bit_cast(unsigned, r);
}
__device__ __forceinline__ f16x8 pack8h(float4 a0, float4 a1) {
    union { unsigned u[4]; f16x8 v; } r;
    r.u[0] = pk2h(a0.x, a0.y);
    r.u[1] = pk2h(a0.z, a0.w);
    r.u[2] = pk2h(a1.x, a1.y);
    r.u[3] = pk2h(a1.z, a1.w);
    return r.v;
}
__device__ __forceinline__ float2 h2f2(unsigned u) {
    f16x2 h = __builtin_bit_cast(f16x2, u);
    return make_float2((float)h[0], (float)h[1]);
}

// ---------------- CSR build ----------------
__global__ __launch_bounds__(256) void count_kernel(const int* __restrict__ col,
                                                    int* __restrict__ cnt) {
    int i = blockIdx.x * 256 + threadIdx.x;
    if (i < NE) atomicAdd(&cnt[col[i]], 1);
}

__global__ __launch_bounds__(256) void scan1_kernel(const int* __restrict__ cnt,
                                                    int* __restrict__ partial,
                                                    int* __restrict__ bsum,
                                                    float* __restrict__ dinv) {
    __shared__ int s[256];
    int i = blockIdx.x * 256 + threadIdx.x;
    int v = (i < NN) ? cnt[i] : 0;
    if (i < NN) dinv[i] = (v > 0) ? 1.0f / sqrtf((float)v) : 0.0f;
    s[threadIdx.x] = v;
    __syncthreads();
    for (int o = 1; o < 256; o <<= 1) {
        int t = (threadIdx.x >= o) ? s[threadIdx.x - o] : 0;
        __syncthreads();
        s[threadIdx.x] += t;
        __syncthreads();
    }
    if (i < NN) partial[i] = s[threadIdx.x] - v;
    if (threadIdx.x == 255) bsum[blockIdx.x] = s[255];
}

__global__ __launch_bounds__(256) void scan2_kernel(int* __restrict__ bsum) {
    __shared__ int s[256];
    int v = (threadIdx.x < NB_SCAN) ? bsum[threadIdx.x] : 0;
    s[threadIdx.x] = v;
    __syncthreads();
    for (int o = 1; o < 256; o <<= 1) {
        int t = (threadIdx.x >= o) ? s[threadIdx.x - o] : 0;
        __syncthreads();
        s[threadIdx.x] += t;
        __syncthreads();
    }
    if (threadIdx.x < NB_SCAN) bsum[threadIdx.x] = s[threadIdx.x] - v;
}

__global__ __launch_bounds__(256) void scan3_kernel(const int* __restrict__ partial,
                                                    const int* __restrict__ bsum,
                                                    int* __restrict__ off,
                                                    int* __restrict__ cursor) {
    int i = blockIdx.x * 256 + threadIdx.x;
    if (i < NN) {
        int o = partial[i] + bsum[blockIdx.x];
        off[i] = o;
        cursor[i] = o;
    }
}

__global__ __launch_bounds__(256) void fill_kernel(const int* __restrict__ row,
                                                   const int* __restrict__ col,
                                                   int* __restrict__ cursor,
                                                   int* __restrict__ csr_idx) {
    int e = blockIdx.x * 256 + threadIdx.x;
    if (e < NE) {
        int c = col[e], r = row[e];
        int slot = atomicAdd(&cursor[c], 1);
        csr_idx[slot] = r;
    }
}

// ---------------- edge sort by src bucket (s>>8): 3-phase, LDS cursors ----------------
__global__ __launch_bounds__(256) void ehist_kernel(const int* __restrict__ pos,
                                                    const int* __restrict__ neg,
                                                    int* __restrict__ bh,
                                                    int* __restrict__ bcnt) {
    __shared__ int h[NBKT];
    const int t = threadIdx.x;
    if (t < NBKT) h[t] = 0;
    __syncthreads();
    const int base = blockIdx.x * PBLK;
#pragma unroll
    for (int j = 0; j < 8; ++j) {
        int i = base + t + j * 256;
        if (i < 2 * NEP) {
            int s = (i < NEP) ? pos[2 * i] : neg[2 * (i - NEP)];
            atomicAdd(&h[s >> 8], 1);
        }
    }
    __syncthreads();
    if (t < NBKT) {
        bh[blockIdx.x * NBKT + t] = h[t];
        if (h[t]) atomicAdd(&bcnt[t], h[t]);
    }
}

__global__ __launch_bounds__(256) void escan_kernel(const int* __restrict__ bcnt,
                                                    int* __restrict__ base) {
    __shared__ int s[256];
    const int t = threadIdx.x;
    int v = (t < NBKT) ? bcnt[t] : 0;
    s[t] = v;
    __syncthreads();
    for (int o = 1; o < 256; o <<= 1) {
        int x = (t >= o) ? s[t - o] : 0;
        __syncthreads();
        s[t] += x;
        __syncthreads();
    }
    if (t < NBKT) base[t] = s[t] - v;
}

__global__ __launch_bounds__(256) void bscan_kernel(const int* __restrict__ bh,
                                                    int* __restrict__ obh) {
    __shared__ int p[256];
    const int b = blockIdx.x;
    const int t = threadIdx.x;
    int v0 = (2 * t < NPB) ? bh[(size_t)(2 * t) * NBKT + b] : 0;
    int v1 = (2 * t + 1 < NPB) ? bh[(size_t)(2 * t + 1) * NBKT + b] : 0;
    p[t] = v0 + v1;
    __syncthreads();
    for (int o = 1; o < 256; o <<= 1) {
        int x = (t >= o) ? p[t - o] : 0;
        __syncthreads();
        p[t] += x;
        __syncthreads();
    }
    int excl = (t > 0) ? p[t - 1] : 0;
    if (2 * t < NPB) obh[(size_t)(2 * t) * NBKT + b] = excl;
    if (2 * t + 1 < NPB) obh[(size_t)(2 * t + 1) * NBKT + b] = excl + v0;
}

__global__ __launch_bounds__(256) void epermute_kernel(const int* __restrict__ pos,
                                                       const int* __restrict__ neg,
                                                       const int* __restrict__ base,
                                                       const int* __restrict__ obh,
                                                       uint2* __restrict__ sd,
                                                       int* __restrict__ oidx) {
    __shared__ int cur[NBKT];
    const int t = threadIdx.x;
    if (t < NBKT) cur[t] = base[t] + obh[(size_t)blockIdx.x * NBKT + t];
    __syncthreads();
    const int bb = blockIdx.x * PBLK;
#pragma unroll
    for (int j = 0; j < 8; ++j) {
        int i = bb + t + j * 256;
        if (i < 2 * NEP) {
            int s, d;
            if (i < NEP) { s = pos[2 * i]; d = pos[2 * i + 1]; }
            else { s = neg[2 * (i - NEP)]; d = neg[2 * (i - NEP) + 1]; }
            int slot = atomicAdd(&cur[s >> 8], 1);
            sd[slot] = make_uint2((unsigned)s, (unsigned)d);
            oidx[slot] = i;
        }
    }
}

// ---------------- all weights -> MFMA B-fragment order, f16 (single launch) ----------------
__global__ __launch_bounds__(256) void wfrag_all_kernel(const float* __restrict__ w1,
                                                        const float* __restrict__ wc,
                                                        const float* __restrict__ w0,
                                                        const float* __restrict__ wl1,
                                                        ushort* __restrict__ w1f,
                                                        ushort* __restrict__ wcf,
                                                        ushort* __restrict__ wc0f,
                                                        ushort* __restrict__ wc1f) {
    int tid = blockIdx.x * 256 + threadIdx.x;  // [0, 20480)
    int g = tid >> 9;
    const float* w;
    ushort* wf;
    int ks;
    if (g < 8) { w = w1; wf = w1f; ks = g; }
    else if (g < 32) { w = wc; wf = wcf; ks = g - 8; }
    else if (g < 36) { w = w0; wf = wc0f; ks = g - 32; }
    else { w = wl1; wf = wc1f; ks = g - 36; }
    int nt = (tid >> 6) & 7, l = tid & 63;
    int kbase = ks * 32 + ((l >> 4) << 3);
    int colq = nt * 16 + (l & 15);
    ushort r[8];
#pragma unroll
    for (int j = 0; j < 8; ++j) r[j] = f2h(w[(size_t)(kbase + j) * HD + colq]);
    *(uint4*)&wf[(size_t)((ks * 8 + nt) * 64 + l) * 8] = *(uint4*)r;
}

// ---------------- MFMA matmul (fp32 A), double-buffered; optional row-scale (dinv) or chem epilogue ----------------
template <int KS, bool EPI, bool ROWSCALE>
__global__ __launch_bounds__(256) void feat_mfma_kernel(const float* __restrict__ A,
                                                        const ushort* __restrict__ wf,
                                                        const float* __restrict__ bias,
                                                        const float* __restrict__ mask,
                                                        const float* __restrict__ rscale,
                                                        ushort* __restrict__ out,
                                                        int ostride, int ooff) {
    __shared__ float At[2][64][36];
    const int t = threadIdx.x;
    const int w = t >> 6, lane = t & 63;
    const int rowBase = blockIdx.x * 64;
    const int nt0 = w * 2;
    const int K = KS * 32;

    const int sr0 = t >> 3, sr1 = 32 + (t >> 3), sc4 = (t & 7) * 4;
    const int g0 = rowBase + sr0, g1 = rowBase + sr1;

    float4 p0 = make_float4(0.f, 0.f, 0.f, 0.f), p1 = p0;
    if (g0 < NN) p0 = *(const float4*)&A[(size_t)g0 * K + sc4];
    if (g1 < NN) p1 = *(const float4*)&A[(size_t)g1 * K + sc4];

    f32x4 acc[4][2] = {};

    for (int ks = 0; ks < KS; ++ks) {
        const int b = ks & 1;
        *(float4*)&At[b][sr0][sc4] = p0;
        *(float4*)&At[b][sr1][sc4] = p1;
        __syncthreads();
        if (ks + 1 < KS) {
            p0 = make_float4(0.f, 0.f, 0.f, 0.f); p1 = p0;
            if (g0 < NN) p0 = *(const float4*)&A[(size_t)g0 * K + (ks + 1) * 32 + sc4];
            if (g1 < NN) p1 = *(const float4*)&A[(size_t)g1 * K + (ks + 1) * 32 + sc4];
        }
        f16x8 bf0 = ((const f16x8*)wf)[(ks * 8 + nt0) * 64 + lane];
        f16x8 bf1 = ((const f16x8*)wf)[(ks * 8 + nt0 + 1) * 64 + lane];
#pragma unroll
        for (int mt = 0; mt < 4; ++mt) {
            int row = mt * 16 + (lane & 15);
            float4 a0 = *(const float4*)&At[b][row][(lane >> 4) * 8];
            float4 a1 = *(const float4*)&At[b][row][(lane >> 4) * 8 + 4];
            f16x8 af = pack8h(a0, a1);
            acc[mt][0] = __builtin_amdgcn_mfma_f32_16x16x32_f16(af, bf0, acc[mt][0], 0, 0, 0);
            acc[mt][1] = __builtin_amdgcn_mfma_f32_16x16x32_f16(af, bf1, acc[mt][1], 0, 0, 0);
        }
    }

    const int c0 = lane & 15, rq = lane >> 4;
    float bb0 = EPI ? bias[nt0 * 16 + c0] : 0.f;
    float bb1 = EPI ? bias[nt0 * 16 + 16 + c0] : 0.f;
#pragma unroll
    for (int mt = 0; mt < 4; ++mt) {
#pragma unroll
        for (int reg = 0; reg < 4; ++reg) {
            int grow = rowBase + mt * 16 + rq * 4 + reg;
            if (grow < NN) {
                float v0 = acc[mt][0][reg], v1 = acc[mt][1][reg];
                if (EPI) {
                    float m = mask[grow];
                    v0 = fmaxf(v0 + bb0, 0.f) * m;
                    v1 = fmaxf(v1 + bb1, 0.f) * m;
                }
                if (ROWSCALE) {
                    float rs = rscale[grow];
                    v0 *= rs;
                    v1 *= rs;
                }
                out[(size_t)grow * ostride + ooff + nt0 * 16 + c0] = f2h(v0);
                out[(size_t)grow * ostride + ooff + nt0 * 16 + 16 + c0] = f2h(v1);
            }
        }
    }
}

// ---------------- MFMA matmul (f16 A, K=128), double-buffered, row-scaled out ----------------
__global__ __launch_bounds__(256) void feat_mfma_f16a_kernel(const ushort* __restrict__ A,
                                                             const ushort* __restrict__ wf,
                                                             const float* __restrict__ rscale,
                                                             ushort* __restrict__ out) {
    __shared__ ushort At[2][64][40];
    const int t = threadIdx.x;
    const int w = t >> 6, lane = t & 63;
    const int rowBase = blockIdx.x * 64;
    const int nt0 = w * 2;

    const int sr = t >> 2, sc = (t & 3) * 8;
    const int g = rowBase + sr;

    uint4 p = make_uint4(0, 0, 0, 0);
    if (g < NN) p = *(const uint4*)&A[(size_t)g * HD + sc];

    f32x4 acc[4][2] = {};

    for (int ks = 0; ks < 4; ++ks) {
        const int b = ks & 1;
        *(uint4*)&At[b][sr][sc] = p;
        __syncthreads();
        if (ks + 1 < 4) {
            p = make_uint4(0, 0, 0, 0);
            if (g < NN) p = *(const uint4*)&A[(size_t)g * HD + (ks + 1) * 32 + sc];
        }
        f16x8 bf0 = ((const f16x8*)wf)[(ks * 8 + nt0) * 64 + lane];
        f16x8 bf1 = ((const f16x8*)wf)[(ks * 8 + nt0 + 1) * 64 + lane];
#pragma unroll
        for (int mt = 0; mt < 4; ++mt) {
            int row = mt * 16 + (lane & 15);
            f16x8 af = *(const f16x8*)&At[b][row][(lane >> 4) * 8];
            acc[mt][0] = __builtin_amdgcn_mfma_f32_16x16x32_f16(af, bf0, acc[mt][0], 0, 0, 0);
            acc[mt][1] = __builtin_amdgcn_mfma_f32_16x16x32_f16(af, bf1, acc[mt][1], 0, 0, 0);
        }
    }

    const int c0 = lane & 15, rq = lane >> 4;
#pragma unroll
    for (int mt = 0; mt < 4; ++mt) {
#pragma unroll
        for (int reg = 0; reg < 4; ++reg) {
            int grow = rowBase + mt * 16 + rq * 4 + reg;
            if (grow < NN) {
                float rs = rscale[grow];
                out[(size_t)grow * HD + nt0 * 16 + c0] = f2h(acc[mt][0][reg] * rs);
                out[(size_t)grow * HD + nt0 * 16 + 16 + c0] = f2h(acc[mt][1][reg] * rs);
            }
        }
    }
}

// ---------------- CSR pull aggregation (h pre-scaled by dinv[src]): 2 rows/wave ----------------
__global__ __launch_bounds__(256) void gather_kernel(const int* __restrict__ off,
                                                     const int* __restrict__ cnt,
                                                     const int* __restrict__ csr_idx,
                                                     const float* __restrict__ dinv,
                                                     const ushort* __restrict__ h,
                                                     const float* __restrict__ bias,
                                                     ushort* __restrict__ zb,
                                                     int ostride) {
    int v = blockIdx.x * 4 + (threadIdx.x >> 6);
    if (v >= NN) return;
    const int lane = threadIdx.x & 63;
    const int half = lane >> 5, sl = lane & 31;
    const int s = off[v];
    const int e = s + cnt[v];
    float4 acc = make_float4(0.f, 0.f, 0.f, 0.f);
    int b = s;
    for (; b + 7 < e; b += 8) {
        int i0 = b + half, i1 = b + 2 + half, i2 = b + 4 + half, i3 = b + 6 + half;
        int r0 = csr_idx[i0], r1 = csr_idx[i1], r2 = csr_idx[i2], r3 = csr_idx[i3];
        uint2 u0 = *(const uint2*)&h[(size_t)r0 * HD + sl * 4];
        uint2 u1 = *(const uint2*)&h[(size_t)r1 * HD + sl * 4];
        uint2 u2 = *(const uint2*)&h[(size_t)r2 * HD + sl * 4];
        uint2 u3 = *(const uint2*)&h[(size_t)r3 * HD + sl * 4];
        float2 a0 = h2f2(u0.x), c0 = h2f2(u0.y);
        float2 a1 = h2f2(u1.x), c1 = h2f2(u1.y);
        float2 a2 = h2f2(u2.x), c2 = h2f2(u2.y);
        float2 a3 = h2f2(u3.x), c3 = h2f2(u3.y);
        acc.x += a0.x + a1.x + a2.x + a3.x;
        acc.y += a0.y + a1.y + a2.y + a3.y;
        acc.z += c0.x + c1.x + c2.x + c3.x;
        acc.w += c0.y + c1.y + c2.y + c3.y;
    }
    for (; b < e; b += 2) {
        int i = b + half;
        if (i < e) {
            int r = csr_idx[i];
            uint2 u = *(const uint2*)&h[(size_t)r * HD + sl * 4];
            float2 a = h2f2(u.x), c = h2f2(u.y);
            acc.x += a.x; acc.y += a.y;
            acc.z += c.x; acc.w += c.y;
        }
    }
    acc.x += __shfl_xor(acc.x, 32);
    acc.y += __shfl_xor(acc.y, 32);
    acc.z += __shfl_xor(acc.z, 32);
    acc.w += __shfl_xor(acc.w, 32);
    if (half == 0) {
        float dv = dinv[v];
        float4 bb = *(const float4*)&bias[sl * 4];
        float o0 = fmaxf(fmaf(acc.x, dv, bb.x), 0.f);
        float o1 = fmaxf(fmaf(acc.y, dv, bb.y), 0.f);
        float o2 = fmaxf(fmaf(acc.z, dv, bb.z), 0.f);
        float o3 = fmaxf(fmaf(acc.w, dv, bb.w), 0.f);
        uint2 pk;
        pk.x = pk2h(o0, o1);
        pk.y = pk2h(o2, o3);
        *(uint2*)&zb[(size_t)v * ostride + sl * 4] = pk;
    }
}

// ---------------- decoder: f16 MFMA, staged product LDS, sorted edges (R16 form) ----------------
__global__ __launch_bounds__(256, 4) void decode_mfma_kernel(const uint2* __restrict__ sedges,
                                                             const int* __restrict__ soidx,
                                                             const ushort* __restrict__ feat,
                                                             const ushort* __restrict__ w1f,
                                                             const float* __restrict__ b1,
                                                             const float* __restrict__ w2,
                                                             const float* __restrict__ b2,
                                                             float* __restrict__ out) {
    __shared__ ushort Flds[8 * 4 * 64 * 8];  // 32 KB; reused for epilogue partials
    const int t = threadIdx.x;
    const int w = t >> 6, lane = t & 63;

    // bijective XCD-chunked swizzle (m204)
    const int nwg = gridDim.x;
    const int orig = blockIdx.x;
    const int q = nwg >> 3, r = nwg & 7;
    const int xcd = orig & 7, k = orig >> 3;
    const int wgid = (xcd < r ? xcd * (q + 1) : r * (q + 1) + (xcd - r) * q) + k;
    const int ebase = wgid * 64;

    const int seg = t & 31, eslot = t >> 5;

    uint2 sdv[8];
#pragma unroll
    for (int j = 0; j < 8; ++j) sdv[j] = sedges[ebase + j * 8 + eslot];
    __builtin_amdgcn_sched_barrier(0);
    uint4 av[8], bv[8];
#pragma unroll
    for (int j = 0; j < 8; ++j) {
        av[j] = *(const uint4*)&feat[(size_t)sdv[j].x * FSTR + seg * 8];
        bv[j] = *(const uint4*)&feat[(size_t)sdv[j].y * FSTR + seg * 8];
    }
    __builtin_amdgcn_sched_barrier(0);
#pragma unroll
    for (int j = 0; j < 8; ++j) {
        int e = j * 8 + eslot;
        uint4 res;
        res.x = h2mul(av[j].x, bv[j].x);
        res.y = h2mul(av[j].y, bv[j].y);
        res.z = h2mul(av[j].z, bv[j].z);
        res.w = h2mul(av[j].w, bv[j].w);
        int ks = seg >> 2;
        int mt = e >> 4;
        int fl = (e & 15) | ((seg & 3) << 4);
        int swz = (seg & 3) | ((ks & 1) << 2);
        ((uint4*)Flds)[(ks * 4 + mt) * 64 + (fl ^ swz)] = res;
    }
    __syncthreads();

    f32x4 acc[4][2] = {};
    const int nt0 = w * 2;
#pragma unroll
    for (int ks = 0; ks < 8; ++ks) {
        f16x8 bf0 = ((const f16x8*)w1f)[(ks * 8 + nt0) * 64 + lane];
        f16x8 bf1 = ((const f16x8*)w1f)[(ks * 8 + nt0 + 1) * 64 + lane];
        const int rswz = ((lane >> 4) & 3) | ((ks & 1) << 2);
#pragma unroll
        for (int mt = 0; mt < 4; ++mt) {
            f16x8 af = ((const f16x8*)Flds)[(ks * 4 + mt) * 64 + (lane ^ rswz)];
            acc[mt][0] = __builtin_amdgcn_mfma_f32_16x16x32_f16(af, bf0, acc[mt][0], 0, 0, 0);
            acc[mt][1] = __builtin_amdgcn_mfma_f32_16x16x32_f16(af, bf1, acc[mt][1], 0, 0, 0);
        }
    }
    __syncthreads();  // Flds reads done; reuse as partials

    float* partf = (float*)Flds;  // [4][64]
    const int c0 = lane & 15, rq = lane >> 4;
    float b1v0 = b1[nt0 * 16 + c0], b1v1 = b1[nt0 * 16 + 16 + c0];
    float w2v0 = w2[nt0 * 16 + c0], w2v1 = w2[nt0 * 16 + 16 + c0];
#pragma unroll
    for (int mt = 0; mt < 4; ++mt) {
#pragma unroll
        for (int reg = 0; reg < 4; ++reg) {
            float h0 = fmaxf(acc[mt][0][reg] + b1v0, 0.f);
            float h1 = fmaxf(acc[mt][1][reg] + b1v1, 0.f);
            float p = fmaf(h0, w2v0, h1 * w2v1);
            p += __shfl_xor(p, 1);
            p += __shfl_xor(p, 2);
            p += __shfl_xor(p, 4);
            p += __shfl_xor(p, 8);
            if (c0 == 0) partf[w * 64 + mt * 16 + rq * 4 + reg] = p;
        }
    }
    __syncthreads();
    if (t < 64) {
        out[soidx[ebase + t]] = partf[t] + partf[64 + t] + partf[128 + t] + partf[192 + t] + b2[0];
    }
}

extern "C" void kernel_launch(void* const* d_in, const int* in_sizes, int n_in,
                              void* d_out, int out_size, void* d_ws, size_t ws_size,
                              hipStream_t stream) {
    const int* edge_index = (const int*)d_in[0];
    const float* chemistry = (const float*)d_in[1];
    const int* pos_edge = (const int*)d_in[2];
    const int* neg_edge = (const int*)d_in[3];
    const float* smiles_mask = (const float*)d_in[4];
    const float* node_emb = (const float*)d_in[5];
    const float* conv_w = (const float*)d_in[6];
    const float* conv_b = (const float*)d_in[7];
    const float* chem_w = (const float*)d_in[8];
    const float* chem_b = (const float*)d_in[9];
    const float* dec_w1 = (const float*)d_in[10];
    const float* dec_b1 = (const float*)d_in[11];
    const float* dec_w2 = (const float*)d_in[12];
    const float* dec_b2 = (const float*)d_in[13];
    float* out = (float*)d_out;

    char* ws = (char*)d_ws;
    int* cnt = (int*)(ws + 0);               // 200000 B
    int* bcnt = (int*)(ws + 204800);         // 784 B (memset covers [0, 205824))
    float* dinv = (float*)(ws + 208896);
    int* partial = (int*)(ws + 409600);
    int* off = (int*)(ws + 614400);
    int* cursor = (int*)(ws + 819200);
    int* bsum = (int*)(ws + 1024000);
    int* bbase = (int*)(ws + 1026048);
    int* csr_idx = (int*)(ws + 1048576);     // 4 MB
    ushort* bufZh = (ushort*)(ws + 9437184); // 12.8 MB (f16 z, layer-0 out)
    int* bh = (int*)(ws + 22237184);         // 307 KB
    int* obh = (int*)(ws + 22657184);        // 307 KB
    ushort* hb = (ushort*)(ws + 35037184);   // 12.8 MB (h; reused for sorted edges)
    ushort* feat = (ushort*)(ws + 47837184); // 25.6 MB  [z | c] interleaved
    ushort* w1f = (ushort*)(ws + 73437184);  // 64 KB
    ushort* wcf = (ushort*)(ws + 73502720);  // 192 KB
    ushort* wc0f = (ushort*)(ws + 73699328); // 32 KB
    ushort* wc1f = (ushort*)(ws + 73732096); // 32 KB
    uint2* sort_sd = (uint2*)(ws + 35037184);   // 6.4 MB (hb region, after gather1)
    int* sort_oidx = (int*)(ws + 41437184);     // 3.2 MB

    const int* e_row = edge_index;
    const int* e_col = edge_index + NE;

    // ---- CSR build + weight fragment pack ----
    hipMemsetAsync(ws, 0, 205824, stream);  // cnt + bcnt
    count_kernel<<<(NE + 255) / 256, 256, 0, stream>>>(e_col, cnt);
    scan1_kernel<<<NB_SCAN, 256, 0, stream>>>(cnt, partial, bsum, dinv);
    scan2_kernel<<<1, 256, 0, stream>>>(bsum);
    scan3_kernel<<<NB_SCAN, 256, 0, stream>>>(partial, bsum, off, cursor);
    fill_kernel<<<(NE + 255) / 256, 256, 0, stream>>>(e_row, e_col, cursor, csr_idx);
    wfrag_all_kernel<<<80, 256, 0, stream>>>(dec_w1, chem_w, conv_w, conv_w + HD * HD,
                                             w1f, wcf, wc0f, wc1f);

    const int mmGrid = (NN + 63) / 64;
    const int gaGrid = (NN + 3) / 4;

    // layer 0: h' = (node_emb @ W0) * dinv[row]  (MFMA), aggregate -> f16 z (bufZh)
    feat_mfma_kernel<4, false, true><<<mmGrid, 256, 0, stream>>>(node_emb, wc0f, nullptr, nullptr, dinv, hb, HD, 0);
    gather_kernel<<<gaGrid, 256, 0, stream>>>(off, cnt, csr_idx, dinv, hb, conv_b, bufZh, HD);

    // layer 1: h' = (z @ W1) * dinv[row]  (f16-A MFMA), aggregate -> f16 z into feat[:,0:128]
    feat_mfma_f16a_kernel<<<mmGrid, 256, 0, stream>>>(bufZh, wc1f, dinv, hb);
    gather_kernel<<<gaGrid, 256, 0, stream>>>(off, cnt, csr_idx, dinv, hb, conv_b + HD, feat, FSTR);

    // ---- edge sort (scratch in freed regions; hb dead after gather1) ----
    ehist_kernel<<<NPB, 256, 0, stream>>>(pos_edge, neg_edge, bh, bcnt);
    escan_kernel<<<1, 256, 0, stream>>>(bcnt, bbase);
    bscan_kernel<<<NBKT, 256, 0, stream>>>(bh, obh);
    epermute_kernel<<<NPB, 256, 0, stream>>>(pos_edge, neg_edge, bbase, obh, sort_sd, sort_oidx);

    // chemistry features -> feat[:,128:256]
    feat_mfma_kernel<24, true, false><<<mmGrid, 256, 0, stream>>>(chemistry, wcf, chem_b, smiles_mask, nullptr, feat, FSTR, HD);

    // decode (pos+neg together, sorted order, scatter by original index)
    decode_mfma_kernel<<<2 * NEP / 64, 256, 0, stream>>>(sort_sd, sort_oidx, feat, w1f,
                                                         dec_b1, dec_w2, dec_b2, out);
}

// Round 19
// 404.452 us; speedup vs baseline: 1.0590x; 1.0226x over previous
//
#include <hip/hip_runtime.h>
#include <hip/hip_fp16.h>

#define NN 50000
#define NE 1000000
#define NEP 400000
#define HD 128
#define CD 768
#define NB_SCAN 196  // ceil(NN/256)
#define FSTR 256     // feat row stride (ushorts): [z(128) | c(128)]
#define NBKT 196     // sort buckets: key = s >> 8
#define PBLK 2048    // edges per permute block
#define NPB ((2 * NEP + PBLK - 1) / PBLK)  // 391

typedef _Float16 f16x8 __attribute__((ext_vector_type(8)));
typedef _Float16 f16x2 __attribute__((ext_vector_type(2)));
typedef __fp16 hf16x2 __attribute__((ext_vector_type(2)));
typedef __attribute__((ext_vector_type(4))) float f32x4;

__device__ __forceinline__ unsigned pk2h(float a, float b) {
    hf16x2 p = __builtin_amdgcn_cvt_pkrtz(a, b);
    return __builtin_bit_cast(unsigned, p);
}
__device__ __forceinline__ ushort f2h(float x) {
    return (ushort)(pk2h(x, 0.f) & 0xffffu);
}
__device__ __forceinline__ unsigned h2mul(unsigned a, unsigned b) {
    f16x2 ha = __builtin_bit_cast(f16x2, a);
    f16x2 hb = __builtin_bit_cast(f16x2, b);
    f16x2 r = ha * hb;
    return __builtin_bit_cast(unsigned, r);
}
__device__ __forceinline__ f16x8 pack8h(float4 a0, float4 a1) {
    union { unsigned u[4]; f16x8 v; } r;
    r.u[0] = pk2h(a0.x, a0.y);
    r.u[1] = pk2h(a0.z, a0.w);
    r.u[2] = pk2h(a1.x, a1.y);
    r.u[3] = pk2h(a1.z, a1.w);
    return r.v;
}
__device__ __forceinline__ float2 h2f2(unsigned u) {
    f16x2 h = __builtin_bit_cast(f16x2, u);
    return make_float2((float)h[0], (float)h[1]);
}

// ---------------- CSR build ----------------
__global__ __launch_bounds__(256) void count_kernel(const int* __restrict__ col,
                                                    int* __restrict__ cnt) {
    int i = blockIdx.x * 256 + threadIdx.x;
    if (i < NE) atomicAdd(&cnt[col[i]], 1);
}

__global__ __launch_bounds__(256) void scan1_kernel(const int* __restrict__ cnt,
                                                    int* __restrict__ partial,
                                                    int* __restrict__ bsum,
                                                    float* __restrict__ dinv) {
    __shared__ int s[256];
    int i = blockIdx.x * 256 + threadIdx.x;
    int v = (i < NN) ? cnt[i] : 0;
    if (i < NN) dinv[i] = (v > 0) ? 1.0f / sqrtf((float)v) : 0.0f;
    s[threadIdx.x] = v;
    __syncthreads();
    for (int o = 1; o < 256; o <<= 1) {
        int t = (threadIdx.x >= o) ? s[threadIdx.x - o] : 0;
        __syncthreads();
        s[threadIdx.x] += t;
        __syncthreads();
    }
    if (i < NN) partial[i] = s[threadIdx.x] - v;
    if (threadIdx.x == 255) bsum[blockIdx.x] = s[255];
}

__global__ __launch_bounds__(256) void scan2_kernel(int* __restrict__ bsum) {
    __shared__ int s[256];
    int v = (threadIdx.x < NB_SCAN) ? bsum[threadIdx.x] : 0;
    s[threadIdx.x] = v;
    __syncthreads();
    for (int o = 1; o < 256; o <<= 1) {
        int t = (threadIdx.x >= o) ? s[threadIdx.x - o] : 0;
        __syncthreads();
        s[threadIdx.x] += t;
        __syncthreads();
    }
    if (threadIdx.x < NB_SCAN) bsum[threadIdx.x] = s[threadIdx.x] - v;
}

__global__ __launch_bounds__(256) void scan3_kernel(const int* __restrict__ partial,
                                                    const int* __restrict__ bsum,
                                                    int* __restrict__ off,
                                                    int* __restrict__ cursor) {
    int i = blockIdx.x * 256 + threadIdx.x;
    if (i < NN) {
        int o = partial[i] + bsum[blockIdx.x];
        off[i] = o;
        cursor[i] = o;
    }
}

__global__ __launch_bounds__(256) void fill_kernel(const int* __restrict__ row,
                                                   const int* __restrict__ col,
                                                   int* __restrict__ cursor,
                                                   int* __restrict__ csr_idx) {
    int e = blockIdx.x * 256 + threadIdx.x;
    if (e < NE) {
        int c = col[e], r = row[e];
        int slot = atomicAdd(&cursor[c], 1);
        csr_idx[slot] = r;
    }
}

// ---------------- edge sort by src bucket (s>>8): 3-phase, LDS cursors ----------------
__global__ __launch_bounds__(256) void ehist_kernel(const int* __restrict__ pos,
                                                    const int* __restrict__ neg,
                                                    int* __restrict__ bh,
                                                    int* __restrict__ bcnt) {
    __shared__ int h[NBKT];
    const int t = threadIdx.x;
    if (t < NBKT) h[t] = 0;
    __syncthreads();
    const int base = blockIdx.x * PBLK;
#pragma unroll
    for (int j = 0; j < 8; ++j) {
        int i = base + t + j * 256;
        if (i < 2 * NEP) {
            int s = (i < NEP) ? pos[2 * i] : neg[2 * (i - NEP)];
            atomicAdd(&h[s >> 8], 1);
        }
    }
    __syncthreads();
    if (t < NBKT) {
        bh[blockIdx.x * NBKT + t] = h[t];
        if (h[t]) atomicAdd(&bcnt[t], h[t]);
    }
}

__global__ __launch_bounds__(256) void escan_kernel(const int* __restrict__ bcnt,
                                                    int* __restrict__ base) {
    __shared__ int s[256];
    const int t = threadIdx.x;
    int v = (t < NBKT) ? bcnt[t] : 0;
    s[t] = v;
    __syncthreads();
    for (int o = 1; o < 256; o <<= 1) {
        int x = (t >= o) ? s[t - o] : 0;
        __syncthreads();
        s[t] += x;
        __syncthreads();
    }
    if (t < NBKT) base[t] = s[t] - v;
}

__global__ __launch_bounds__(256) void bscan_kernel(const int* __restrict__ bh,
                                                    int* __restrict__ obh) {
    __shared__ int p[256];
    const int b = blockIdx.x;
    const int t = threadIdx.x;
    int v0 = (2 * t < NPB) ? bh[(size_t)(2 * t) * NBKT + b] : 0;
    int v1 = (2 * t + 1 < NPB) ? bh[(size_t)(2 * t + 1) * NBKT + b] : 0;
    p[t] = v0 + v1;
    __syncthreads();
    for (int o = 1; o < 256; o <<= 1) {
        int x = (t >= o) ? p[t - o] : 0;
        __syncthreads();
        p[t] += x;
        __syncthreads();
    }
    int excl = (t > 0) ? p[t - 1] : 0;
    if (2 * t < NPB) obh[(size_t)(2 * t) * NBKT + b] = excl;
    if (2 * t + 1 < NPB) obh[(size_t)(2 * t + 1) * NBKT + b] = excl + v0;
}

__global__ __launch_bounds__(256) void epermute_kernel(const int* __restrict__ pos,
                                                       const int* __restrict__ neg,
                                                       const int* __restrict__ base,
                                                       const int* __restrict__ obh,
                                                       uint2* __restrict__ sd,
                                                       int* __restrict__ oidx) {
    __shared__ int cur[NBKT];
    const int t = threadIdx.x;
    if (t < NBKT) cur[t] = base[t] + obh[(size_t)blockIdx.x * NBKT + t];
    __syncthreads();
    const int bb = blockIdx.x * PBLK;
#pragma unroll
    for (int j = 0; j < 8; ++j) {
        int i = bb + t + j * 256;
        if (i < 2 * NEP) {
            int s, d;
            if (i < NEP) { s = pos[2 * i]; d = pos[2 * i + 1]; }
            else { s = neg[2 * (i - NEP)]; d = neg[2 * (i - NEP) + 1]; }
            int slot = atomicAdd(&cur[s >> 8], 1);
            sd[slot] = make_uint2((unsigned)s, (unsigned)d);
            oidx[slot] = i;
        }
    }
}

// ---------------- all weights -> MFMA B-fragment order, f16 (single launch) ----------------
__global__ __launch_bounds__(256) void wfrag_all_kernel(const float* __restrict__ w1,
                                                        const float* __restrict__ wc,
                                                        const float* __restrict__ w0,
                                                        const float* __restrict__ wl1,
                                                        ushort* __restrict__ w1f,
                                                        ushort* __restrict__ wcf,
                                                        ushort* __restrict__ wc0f,
                                                        ushort* __restrict__ wc1f) {
    int tid = blockIdx.x * 256 + threadIdx.x;  // [0, 20480)
    int g = tid >> 9;
    const float* w;
    ushort* wf;
    int ks;
    if (g < 8) { w = w1; wf = w1f; ks = g; }
    else if (g < 32) { w = wc; wf = wcf; ks = g - 8; }
    else if (g < 36) { w = w0; wf = wc0f; ks = g - 32; }
    else { w = wl1; wf = wc1f; ks = g - 36; }
    int nt = (tid >> 6) & 7, l = tid & 63;
    int kbase = ks * 32 + ((l >> 4) << 3);
    int colq = nt * 16 + (l & 15);
    ushort r[8];
#pragma unroll
    for (int j = 0; j < 8; ++j) r[j] = f2h(w[(size_t)(kbase + j) * HD + colq]);
    *(uint4*)&wf[(size_t)((ks * 8 + nt) * 64 + l) * 8] = *(uint4*)r;
}

// ---------------- MFMA matmul (fp32 A), double-buffered; optional row-scale (dinv) or chem epilogue ----------------
template <int KS, bool EPI, bool ROWSCALE>
__global__ __launch_bounds__(256) void feat_mfma_kernel(const float* __restrict__ A,
                                                        const ushort* __restrict__ wf,
                                                        const float* __restrict__ bias,
                                                        const float* __restrict__ mask,
                                                        const float* __restrict__ rscale,
                                                        ushort* __restrict__ out,
                                                        int ostride, int ooff) {
    __shared__ float At[2][64][36];
    const int t = threadIdx.x;
    const int w = t >> 6, lane = t & 63;
    const int rowBase = blockIdx.x * 64;
    const int nt0 = w * 2;
    const int K = KS * 32;

    const int sr0 = t >> 3, sr1 = 32 + (t >> 3), sc4 = (t & 7) * 4;
    const int g0 = rowBase + sr0, g1 = rowBase + sr1;

    float4 p0 = make_float4(0.f, 0.f, 0.f, 0.f), p1 = p0;
    if (g0 < NN) p0 = *(const float4*)&A[(size_t)g0 * K + sc4];
    if (g1 < NN) p1 = *(const float4*)&A[(size_t)g1 * K + sc4];

    f32x4 acc[4][2] = {};

    for (int ks = 0; ks < KS; ++ks) {
        const int b = ks & 1;
        *(float4*)&At[b][sr0][sc4] = p0;
        *(float4*)&At[b][sr1][sc4] = p1;
        __syncthreads();
        if (ks + 1 < KS) {
            p0 = make_float4(0.f, 0.f, 0.f, 0.f); p1 = p0;
            if (g0 < NN) p0 = *(const float4*)&A[(size_t)g0 * K + (ks + 1) * 32 + sc4];
            if (g1 < NN) p1 = *(const float4*)&A[(size_t)g1 * K + (ks + 1) * 32 + sc4];
        }
        f16x8 bf0 = ((const f16x8*)wf)[(ks * 8 + nt0) * 64 + lane];
        f16x8 bf1 = ((const f16x8*)wf)[(ks * 8 + nt0 + 1) * 64 + lane];
#pragma unroll
        for (int mt = 0; mt < 4; ++mt) {
            int row = mt * 16 + (lane & 15);
            float4 a0 = *(const float4*)&At[b][row][(lane >> 4) * 8];
            float4 a1 = *(const float4*)&At[b][row][(lane >> 4) * 8 + 4];
            f16x8 af = pack8h(a0, a1);
            acc[mt][0] = __builtin_amdgcn_mfma_f32_16x16x32_f16(af, bf0, acc[mt][0], 0, 0, 0);
            acc[mt][1] = __builtin_amdgcn_mfma_f32_16x16x32_f16(af, bf1, acc[mt][1], 0, 0, 0);
        }
    }

    const int c0 = lane & 15, rq = lane >> 4;
    float bb0 = EPI ? bias[nt0 * 16 + c0] : 0.f;
    float bb1 = EPI ? bias[nt0 * 16 + 16 + c0] : 0.f;
#pragma unroll
    for (int mt = 0; mt < 4; ++mt) {
#pragma unroll
        for (int reg = 0; reg < 4; ++reg) {
            int grow = rowBase + mt * 16 + rq * 4 + reg;
            if (grow < NN) {
                float v0 = acc[mt][0][reg], v1 = acc[mt][1][reg];
                if (EPI) {
                    float m = mask[grow];
                    v0 = fmaxf(v0 + bb0, 0.f) * m;
                    v1 = fmaxf(v1 + bb1, 0.f) * m;
                }
                if (ROWSCALE) {
                    float rs = rscale[grow];
                    v0 *= rs;
                    v1 *= rs;
                }
                out[(size_t)grow * ostride + ooff + nt0 * 16 + c0] = f2h(v0);
                out[(size_t)grow * ostride + ooff + nt0 * 16 + 16 + c0] = f2h(v1);
            }
        }
    }
}

// ---------------- MFMA matmul (f16 A, K=128), double-buffered, row-scaled out ----------------
__global__ __launch_bounds__(256) void feat_mfma_f16a_kernel(const ushort* __restrict__ A,
                                                             const ushort* __restrict__ wf,
                                                             const float* __restrict__ rscale,
                                                             ushort* __restrict__ out) {
    __shared__ ushort At[2][64][40];
    const int t = threadIdx.x;
    const int w = t >> 6, lane = t & 63;
    const int rowBase = blockIdx.x * 64;
    const int nt0 = w * 2;

    const int sr = t >> 2, sc = (t & 3) * 8;
    const int g = rowBase + sr;

    uint4 p = make_uint4(0, 0, 0, 0);
    if (g < NN) p = *(const uint4*)&A[(size_t)g * HD + sc];

    f32x4 acc[4][2] = {};

    for (int ks = 0; ks < 4; ++ks) {
        const int b = ks & 1;
        *(uint4*)&At[b][sr][sc] = p;
        __syncthreads();
        if (ks + 1 < 4) {
            p = make_uint4(0, 0, 0, 0);
            if (g < NN) p = *(const uint4*)&A[(size_t)g * HD + (ks + 1) * 32 + sc];
        }
        f16x8 bf0 = ((const f16x8*)wf)[(ks * 8 + nt0) * 64 + lane];
        f16x8 bf1 = ((const f16x8*)wf)[(ks * 8 + nt0 + 1) * 64 + lane];
#pragma unroll
        for (int mt = 0; mt < 4; ++mt) {
            int row = mt * 16 + (lane & 15);
            f16x8 af = *(const f16x8*)&At[b][row][(lane >> 4) * 8];
            acc[mt][0] = __builtin_amdgcn_mfma_f32_16x16x32_f16(af, bf0, acc[mt][0], 0, 0, 0);
            acc[mt][1] = __builtin_amdgcn_mfma_f32_16x16x32_f16(af, bf1, acc[mt][1], 0, 0, 0);
        }
    }

    const int c0 = lane & 15, rq = lane >> 4;
#pragma unroll
    for (int mt = 0; mt < 4; ++mt) {
#pragma unroll
        for (int reg = 0; reg < 4; ++reg) {
            int grow = rowBase + mt * 16 + rq * 4 + reg;
            if (grow < NN) {
                float rs = rscale[grow];
                out[(size_t)grow * HD + nt0 * 16 + c0] = f2h(acc[mt][0][reg] * rs);
                out[(size_t)grow * HD + nt0 * 16 + 16 + c0] = f2h(acc[mt][1][reg] * rs);
            }
        }
    }
}

// ---------------- CSR pull aggregation (h pre-scaled by dinv[src]): 2 rows/wave ----------------
__global__ __launch_bounds__(256) void gather_kernel(const int* __restrict__ off,
                                                     const int* __restrict__ cnt,
                                                     const int* __restrict__ csr_idx,
                                                     const float* __restrict__ dinv,
                                                     const ushort* __restrict__ h,
                                                     const float* __restrict__ bias,
                                                     ushort* __restrict__ zb,
                                                     int ostride) {
    int v = blockIdx.x * 4 + (threadIdx.x >> 6);
    if (v >= NN) return;
    const int lane = threadIdx.x & 63;
    const int half = lane >> 5, sl = lane & 31;
    const int s = off[v];
    const int e = s + cnt[v];
    float4 acc = make_float4(0.f, 0.f, 0.f, 0.f);
    int b = s;
    for (; b + 7 < e; b += 8) {
        int i0 = b + half, i1 = b + 2 + half, i2 = b + 4 + half, i3 = b + 6 + half;
        int r0 = csr_idx[i0], r1 = csr_idx[i1], r2 = csr_idx[i2], r3 = csr_idx[i3];
        uint2 u0 = *(const uint2*)&h[(size_t)r0 * HD + sl * 4];
        uint2 u1 = *(const uint2*)&h[(size_t)r1 * HD + sl * 4];
        uint2 u2 = *(const uint2*)&h[(size_t)r2 * HD + sl * 4];
        uint2 u3 = *(const uint2*)&h[(size_t)r3 * HD + sl * 4];
        float2 a0 = h2f2(u0.x), c0 = h2f2(u0.y);
        float2 a1 = h2f2(u1.x), c1 = h2f2(u1.y);
        float2 a2 = h2f2(u2.x), c2 = h2f2(u2.y);
        float2 a3 = h2f2(u3.x), c3 = h2f2(u3.y);
        acc.x += a0.x + a1.x + a2.x + a3.x;
        acc.y += a0.y + a1.y + a2.y + a3.y;
        acc.z += c0.x + c1.x + c2.x + c3.x;
        acc.w += c0.y + c1.y + c2.y + c3.y;
    }
    for (; b < e; b += 2) {
        int i = b + half;
        if (i < e) {
            int r = csr_idx[i];
            uint2 u = *(const uint2*)&h[(size_t)r * HD + sl * 4];
            float2 a = h2f2(u.x), c = h2f2(u.y);
            acc.x += a.x; acc.y += a.y;
            acc.z += c.x; acc.w += c.y;
        }
    }
    acc.x += __shfl_xor(acc.x, 32);
    acc.y += __shfl_xor(acc.y, 32);
    acc.z += __shfl_xor(acc.z, 32);
    acc.w += __shfl_xor(acc.w, 32);
    if (half == 0) {
        float dv = dinv[v];
        float4 bb = *(const float4*)&bias[sl * 4];
        float o0 = fmaxf(fmaf(acc.x, dv, bb.x), 0.f);
        float o1 = fmaxf(fmaf(acc.y, dv, bb.y), 0.f);
        float o2 = fmaxf(fmaf(acc.z, dv, bb.z), 0.f);
        float o3 = fmaxf(fmaf(acc.w, dv, bb.w), 0.f);
        uint2 pk;
        pk.x = pk2h(o0, o1);
        pk.y = pk2h(o2, o3);
        *(uint2*)&zb[(size_t)v * ostride + sl * 4] = pk;
    }
}

// ---------------- decoder: 32-edge blocks, 16KB LDS, 6 blocks/CU ----------------
// wave w covers nt pair (2w, 2w+1) for both 16-edge M-tiles.
__global__ __launch_bounds__(256, 6) void decode_mfma_kernel(const uint2* __restrict__ sedges,
                                                             const int* __restrict__ soidx,
                                                             const ushort* __restrict__ feat,
                                                             const ushort* __restrict__ w1f,
                                                             const float* __restrict__ b1,
                                                             const float* __restrict__ w2,
                                                             const float* __restrict__ b2,
                                                             float* __restrict__ out) {
    __shared__ ushort Flds[8 * 2 * 64 * 8];  // 16 KB; reused for epilogue partials
    const int t = threadIdx.x;
    const int w = t >> 6, lane = t & 63;

    // bijective XCD-chunked swizzle (m204)
    const int nwg = gridDim.x;
    const int orig = blockIdx.x;
    const int q = nwg >> 3, r = nwg & 7;
    const int xcd = orig & 7, k = orig >> 3;
    const int wgid = (xcd < r ? xcd * (q + 1) : r * (q + 1) + (xcd - r) * q) + k;
    const int ebase = wgid * 32;

    const int seg = t & 31, eslot = t >> 5;

    uint2 sdv[4];
#pragma unroll
    for (int j = 0; j < 4; ++j) sdv[j] = sedges[ebase + j * 8 + eslot];
    __builtin_amdgcn_sched_barrier(0);
    uint4 av[4], bv[4];
#pragma unroll
    for (int j = 0; j < 4; ++j) {
        av[j] = *(const uint4*)&feat[(size_t)sdv[j].x * FSTR + seg * 8];
        bv[j] = *(const uint4*)&feat[(size_t)sdv[j].y * FSTR + seg * 8];
    }
    __builtin_amdgcn_sched_barrier(0);
#pragma unroll
    for (int j = 0; j < 4; ++j) {
        int e = j * 8 + eslot;  // 0..31
        uint4 res;
        res.x = h2mul(av[j].x, bv[j].x);
        res.y = h2mul(av[j].y, bv[j].y);
        res.z = h2mul(av[j].z, bv[j].z);
        res.w = h2mul(av[j].w, bv[j].w);
        int ks = seg >> 2;
        int mt = e >> 4;
        int fl = (e & 15) | ((seg & 3) << 4);
        int swz = (seg & 3) | ((ks & 1) << 2);
        ((uint4*)Flds)[(ks * 2 + mt) * 64 + (fl ^ swz)] = res;
    }
    __syncthreads();

    f32x4 acc[2][2] = {};
    const int nt0 = w * 2;
#pragma unroll
    for (int ks = 0; ks < 8; ++ks) {
        f16x8 bf0 = ((const f16x8*)w1f)[(ks * 8 + nt0) * 64 + lane];
        f16x8 bf1 = ((const f16x8*)w1f)[(ks * 8 + nt0 + 1) * 64 + lane];
        const int rswz = ((lane >> 4) & 3) | ((ks & 1) << 2);
#pragma unroll
        for (int mt = 0; mt < 2; ++mt) {
            f16x8 af = ((const f16x8*)Flds)[(ks * 2 + mt) * 64 + (lane ^ rswz)];
            acc[mt][0] = __builtin_amdgcn_mfma_f32_16x16x32_f16(af, bf0, acc[mt][0], 0, 0, 0);
            acc[mt][1] = __builtin_amdgcn_mfma_f32_16x16x32_f16(af, bf1, acc[mt][1], 0, 0, 0);
        }
    }
    __syncthreads();  // Flds reads done; reuse as partials

    float* partf = (float*)Flds;  // [4][32]
    const int c0 = lane & 15, rq = lane >> 4;
    float b1v0 = b1[nt0 * 16 + c0], b1v1 = b1[nt0 * 16 + 16 + c0];
    float w2v0 = w2[nt0 * 16 + c0], w2v1 = w2[nt0 * 16 + 16 + c0];
#pragma unroll
    for (int mt = 0; mt < 2; ++mt) {
#pragma unroll
        for (int reg = 0; reg < 4; ++reg) {
            float h0 = fmaxf(acc[mt][0][reg] + b1v0, 0.f);
            float h1 = fmaxf(acc[mt][1][reg] + b1v1, 0.f);
            float p = fmaf(h0, w2v0, h1 * w2v1);
            p += __shfl_xor(p, 1);
            p += __shfl_xor(p, 2);
            p += __shfl_xor(p, 4);
            p += __shfl_xor(p, 8);
            if (c0 == 0) partf[w * 32 + mt * 16 + rq * 4 + reg] = p;
        }
    }
    __syncthreads();
    if (t < 32) {
        out[soidx[ebase + t]] = partf[t] + partf[32 + t] + partf[64 + t] + partf[96 + t] + b2[0];
    }
}

extern "C" void kernel_launch(void* const* d_in, const int* in_sizes, int n_in,
                              void* d_out, int out_size, void* d_ws, size_t ws_size,
                              hipStream_t stream) {
    const int* edge_index = (const int*)d_in[0];
    const float* chemistry = (const float*)d_in[1];
    const int* pos_edge = (const int*)d_in[2];
    const int* neg_edge = (const int*)d_in[3];
    const float* smiles_mask = (const float*)d_in[4];
    const float* node_emb = (const float*)d_in[5];
    const float* conv_w = (const float*)d_in[6];
    const float* conv_b = (const float*)d_in[7];
    const float* chem_w = (const float*)d_in[8];
    const float* chem_b = (const float*)d_in[9];
    const float* dec_w1 = (const float*)d_in[10];
    const float* dec_b1 = (const float*)d_in[11];
    const float* dec_w2 = (const float*)d_in[12];
    const float* dec_b2 = (const float*)d_in[13];
    float* out = (float*)d_out;

    char* ws = (char*)d_ws;
    int* cnt = (int*)(ws + 0);               // 200000 B
    int* bcnt = (int*)(ws + 204800);         // 784 B (memset covers [0, 205824))
    float* dinv = (float*)(ws + 208896);
    int* partial = (int*)(ws + 409600);
    int* off = (int*)(ws + 614400);
    int* cursor = (int*)(ws + 819200);
    int* bsum = (int*)(ws + 1024000);
    int* bbase = (int*)(ws + 1026048);
    int* csr_idx = (int*)(ws + 1048576);     // 4 MB
    ushort* bufZh = (ushort*)(ws + 9437184); // 12.8 MB (f16 z, layer-0 out)
    int* bh = (int*)(ws + 22237184);         // 307 KB
    int* obh = (int*)(ws + 22657184);        // 307 KB
    ushort* hb = (ushort*)(ws + 35037184);   // 12.8 MB (h; reused for sorted edges)
    ushort* feat = (ushort*)(ws + 47837184); // 25.6 MB  [z | c] interleaved
    ushort* w1f = (ushort*)(ws + 73437184);  // 64 KB
    ushort* wcf = (ushort*)(ws + 73502720);  // 192 KB
    ushort* wc0f = (ushort*)(ws + 73699328); // 32 KB
    ushort* wc1f = (ushort*)(ws + 73732096); // 32 KB
    uint2* sort_sd = (uint2*)(ws + 35037184);   // 6.4 MB (hb region, after gather1)
    int* sort_oidx = (int*)(ws + 41437184);     // 3.2 MB

    const int* e_row = edge_index;
    const int* e_col = edge_index + NE;

    // ---- CSR build + weight fragment pack ----
    hipMemsetAsync(ws, 0, 205824, stream);  // cnt + bcnt
    count_kernel<<<(NE + 255) / 256, 256, 0, stream>>>(e_col, cnt);
    scan1_kernel<<<NB_SCAN, 256, 0, stream>>>(cnt, partial, bsum, dinv);
    scan2_kernel<<<1, 256, 0, stream>>>(bsum);
    scan3_kernel<<<NB_SCAN, 256, 0, stream>>>(partial, bsum, off, cursor);
    fill_kernel<<<(NE + 255) / 256, 256, 0, stream>>>(e_row, e_col, cursor, csr_idx);
    wfrag_all_kernel<<<80, 256, 0, stream>>>(dec_w1, chem_w, conv_w, conv_w + HD * HD,
                                             w1f, wcf, wc0f, wc1f);

    const int mmGrid = (NN + 63) / 64;
    const int gaGrid = (NN + 3) / 4;

    // layer 0: h' = (node_emb @ W0) * dinv[row]  (MFMA), aggregate -> f16 z (bufZh)
    feat_mfma_kernel<4, false, true><<<mmGrid, 256, 0, stream>>>(node_emb, wc0f, nullptr, nullptr, dinv, hb, HD, 0);
    gather_kernel<<<gaGrid, 256, 0, stream>>>(off, cnt, csr_idx, dinv, hb, conv_b, bufZh, HD);

    // layer 1: h' = (z @ W1) * dinv[row]  (f16-A MFMA), aggregate -> f16 z into feat[:,0:128]
    feat_mfma_f16a_kernel<<<mmGrid, 256, 0, stream>>>(bufZh, wc1f, dinv, hb);
    gather_kernel<<<gaGrid, 256, 0, stream>>>(off, cnt, csr_idx, dinv, hb, conv_b + HD, feat, FSTR);

    // ---- edge sort (scratch in freed regions; hb dead after gather1) ----
    ehist_kernel<<<NPB, 256, 0, stream>>>(pos_edge, neg_edge, bh, bcnt);
    escan_kernel<<<1, 256, 0, stream>>>(bcnt, bbase);
    bscan_kernel<<<NBKT, 256, 0, stream>>>(bh, obh);
    epermute_kernel<<<NPB, 256, 0, stream>>>(pos_edge, neg_edge, bbase, obh, sort_sd, sort_oidx);

    // chemistry features -> feat[:,128:256]
    feat_mfma_kernel<24, true, false><<<mmGrid, 256, 0, stream>>>(chemistry, wcf, chem_b, smiles_mask, nullptr, feat, FSTR, HD);

    // decode (pos+neg together, sorted order, scatter by original index)
    decode_mfma_kernel<<<2 * NEP / 32, 256, 0, stream>>>(sort_sd, sort_oidx, feat, w1f,
                                                         dec_b1, dec_w2, dec_b2, out);
}

// Round 20
// 402.119 us; speedup vs baseline: 1.0652x; 1.0058x over previous
//
#include <hip/hip_runtime.h>
#include <hip/hip_fp16.h>

#define NN 50000
#define NE 1000000
#define NEP 400000
#define HD 128
#define CD 768
#define NB_SCAN 196  // ceil(NN/256)
#define FSTR 256     // feat row stride (ushorts): [z(128) | c(128)]
#define NBKT 196     // sort buckets: key = s >> 8
#define PBLK 2048    // edges per permute block
#define NPB ((2 * NEP + PBLK - 1) / PBLK)  // 391

typedef _Float16 f16x8 __attribute__((ext_vector_type(8)));
typedef _Float16 f16x2 __attribute__((ext_vector_type(2)));
typedef __fp16 hf16x2 __attribute__((ext_vector_type(2)));
typedef __attribute__((ext_vector_type(4))) float f32x4;

__device__ __forceinline__ unsigned pk2h(float a, float b) {
    hf16x2 p = __builtin_amdgcn_cvt_pkrtz(a, b);
    return __builtin_bit_cast(unsigned, p);
}
__device__ __forceinline__ ushort f2h(float x) {
    return (ushort)(pk2h(x, 0.f) & 0xffffu);
}
__device__ __forceinline__ unsigned h2mul(unsigned a, unsigned b) {
    f16x2 ha = __builtin_bit_cast(f16x2, a);
    f16x2 hb = __builtin_bit_cast(f16x2, b);
    f16x2 r = ha * hb;
    return __builtin_bit_cast(unsigned, r);
}
__device__ __forceinline__ f16x8 pack8h(float4 a0, float4 a1) {
    union { unsigned u[4]; f16x8 v; } r;
    r.u[0] = pk2h(a0.x, a0.y);
    r.u[1] = pk2h(a0.z, a0.w);
    r.u[2] = pk2h(a1.x, a1.y);
    r.u[3] = pk2h(a1.z, a1.w);
    return r.v;
}
__device__ __forceinline__ float2 h2f2(unsigned u) {
    f16x2 h = __builtin_bit_cast(f16x2, u);
    return make_float2((float)h[0], (float)h[1]);
}

// ---------------- CSR build ----------------
__global__ __launch_bounds__(256) void count_kernel(const int* __restrict__ col,
                                                    int* __restrict__ cnt) {
    int i = blockIdx.x * 256 + threadIdx.x;
    if (i < NE) atomicAdd(&cnt[col[i]], 1);
}

__global__ __launch_bounds__(256) void scan1_kernel(const int* __restrict__ cnt,
                                                    int* __restrict__ partial,
                                                    int* __restrict__ bsum,
                                                    float* __restrict__ dinv) {
    __shared__ int s[256];
    int i = blockIdx.x * 256 + threadIdx.x;
    int v = (i < NN) ? cnt[i] : 0;
    if (i < NN) dinv[i] = (v > 0) ? 1.0f / sqrtf((float)v) : 0.0f;
    s[threadIdx.x] = v;
    __syncthreads();
    for (int o = 1; o < 256; o <<= 1) {
        int t = (threadIdx.x >= o) ? s[threadIdx.x - o] : 0;
        __syncthreads();
        s[threadIdx.x] += t;
        __syncthreads();
    }
    if (i < NN) partial[i] = s[threadIdx.x] - v;
    if (threadIdx.x == 255) bsum[blockIdx.x] = s[255];
}

__global__ __launch_bounds__(256) void scan2_kernel(int* __restrict__ bsum) {
    __shared__ int s[256];
    int v = (threadIdx.x < NB_SCAN) ? bsum[threadIdx.x] : 0;
    s[threadIdx.x] = v;
    __syncthreads();
    for (int o = 1; o < 256; o <<= 1) {
        int t = (threadIdx.x >= o) ? s[threadIdx.x - o] : 0;
        __syncthreads();
        s[threadIdx.x] += t;
        __syncthreads();
    }
    if (threadIdx.x < NB_SCAN) bsum[threadIdx.x] = s[threadIdx.x] - v;
}

__global__ __launch_bounds__(256) void scan3_kernel(const int* __restrict__ partial,
                                                    const int* __restrict__ bsum,
                                                    int* __restrict__ off,
                                                    int* __restrict__ cursor) {
    int i = blockIdx.x * 256 + threadIdx.x;
    if (i < NN) {
        int o = partial[i] + bsum[blockIdx.x];
        off[i] = o;
        cursor[i] = o;
    }
}

__global__ __launch_bounds__(256) void fill_kernel(const int* __restrict__ row,
                                                   const int* __restrict__ col,
                                                   int* __restrict__ cursor,
                                                   int* __restrict__ csr_idx) {
    int e = blockIdx.x * 256 + threadIdx.x;
    if (e < NE) {
        int c = col[e], r = row[e];
        int slot = atomicAdd(&cursor[c], 1);
        csr_idx[slot] = r;
    }
}

// ---------------- edge sort by src bucket (s>>8): 3-phase, LDS cursors ----------------
__global__ __launch_bounds__(256) void ehist_kernel(const int* __restrict__ pos,
                                                    const int* __restrict__ neg,
                                                    int* __restrict__ bh,
                                                    int* __restrict__ bcnt) {
    __shared__ int h[NBKT];
    const int t = threadIdx.x;
    if (t < NBKT) h[t] = 0;
    __syncthreads();
    const int base = blockIdx.x * PBLK;
#pragma unroll
    for (int j = 0; j < 8; ++j) {
        int i = base + t + j * 256;
        if (i < 2 * NEP) {
            int s = (i < NEP) ? pos[2 * i] : neg[2 * (i - NEP)];
            atomicAdd(&h[s >> 8], 1);
        }
    }
    __syncthreads();
    if (t < NBKT) {
        bh[blockIdx.x * NBKT + t] = h[t];
        if (h[t]) atomicAdd(&bcnt[t], h[t]);
    }
}

__global__ __launch_bounds__(256) void escan_kernel(const int* __restrict__ bcnt,
                                                    int* __restrict__ base) {
    __shared__ int s[256];
    const int t = threadIdx.x;
    int v = (t < NBKT) ? bcnt[t] : 0;
    s[t] = v;
    __syncthreads();
    for (int o = 1; o < 256; o <<= 1) {
        int x = (t >= o) ? s[t - o] : 0;
        __syncthreads();
        s[t] += x;
        __syncthreads();
    }
    if (t < NBKT) base[t] = s[t] - v;
}

__global__ __launch_bounds__(256) void bscan_kernel(const int* __restrict__ bh,
                                                    int* __restrict__ obh) {
    __shared__ int p[256];
    const int b = blockIdx.x;
    const int t = threadIdx.x;
    int v0 = (2 * t < NPB) ? bh[(size_t)(2 * t) * NBKT + b] : 0;
    int v1 = (2 * t + 1 < NPB) ? bh[(size_t)(2 * t + 1) * NBKT + b] : 0;
    p[t] = v0 + v1;
    __syncthreads();
    for (int o = 1; o < 256; o <<= 1) {
        int x = (t >= o) ? p[t - o] : 0;
        __syncthreads();
        p[t] += x;
        __syncthreads();
    }
    int excl = (t > 0) ? p[t - 1] : 0;
    if (2 * t < NPB) obh[(size_t)(2 * t) * NBKT + b] = excl;
    if (2 * t + 1 < NPB) obh[(size_t)(2 * t + 1) * NBKT + b] = excl + v0;
}

__global__ __launch_bounds__(256) void epermute_kernel(const int* __restrict__ pos,
                                                       const int* __restrict__ neg,
                                                       const int* __restrict__ base,
                                                       const int* __restrict__ obh,
                                                       uint2* __restrict__ sd,
                                                       int* __restrict__ oidx) {
    __shared__ int cur[NBKT];
    const int t = threadIdx.x;
    if (t < NBKT) cur[t] = base[t] + obh[(size_t)blockIdx.x * NBKT + t];
    __syncthreads();
    const int bb = blockIdx.x * PBLK;
#pragma unroll
    for (int j = 0; j < 8; ++j) {
        int i = bb + t + j * 256;
        if (i < 2 * NEP) {
            int s, d;
            if (i < NEP) { s = pos[2 * i]; d = pos[2 * i + 1]; }
            else { s = neg[2 * (i - NEP)]; d = neg[2 * (i - NEP) + 1]; }
            int slot = atomicAdd(&cur[s >> 8], 1);
            sd[slot] = make_uint2((unsigned)s, (unsigned)d);
            oidx[slot] = i;
        }
    }
}

// ---------------- all weights -> MFMA B-fragment order, f16 (single launch) ----------------
__global__ __launch_bounds__(256) void wfrag_all_kernel(const float* __restrict__ w1,
                                                        const float* __restrict__ wc,
                                                        const float* __restrict__ w0,
                                                        const float* __restrict__ wl1,
                                                        ushort* __restrict__ w1f,
                                                        ushort* __restrict__ wcf,
                                                        ushort* __restrict__ wc0f,
                                                        ushort* __restrict__ wc1f) {
    int tid = blockIdx.x * 256 + threadIdx.x;  // [0, 20480)
    int g = tid >> 9;
    const float* w;
    ushort* wf;
    int ks;
    if (g < 8) { w = w1; wf = w1f; ks = g; }
    else if (g < 32) { w = wc; wf = wcf; ks = g - 8; }
    else if (g < 36) { w = w0; wf = wc0f; ks = g - 32; }
    else { w = wl1; wf = wc1f; ks = g - 36; }
    int nt = (tid >> 6) & 7, l = tid & 63;
    int kbase = ks * 32 + ((l >> 4) << 3);
    int colq = nt * 16 + (l & 15);
    ushort r[8];
#pragma unroll
    for (int j = 0; j < 8; ++j) r[j] = f2h(w[(size_t)(kbase + j) * HD + colq]);
    *(uint4*)&wf[(size_t)((ks * 8 + nt) * 64 + l) * 8] = *(uint4*)r;
}

// ---------------- MFMA matmul (fp32 A), double-buffered; optional row-scale (dinv) or chem epilogue ----------------
template <int KS, bool EPI, bool ROWSCALE>
__global__ __launch_bounds__(256) void feat_mfma_kernel(const float* __restrict__ A,
                                                        const ushort* __restrict__ wf,
                                                        const float* __restrict__ bias,
                                                        const float* __restrict__ mask,
                                                        const float* __restrict__ rscale,
                                                        ushort* __restrict__ out,
                                                        int ostride, int ooff) {
    __shared__ float At[2][64][36];
    const int t = threadIdx.x;
    const int w = t >> 6, lane = t & 63;
    const int rowBase = blockIdx.x * 64;
    const int nt0 = w * 2;
    const int K = KS * 32;

    const int sr0 = t >> 3, sr1 = 32 + (t >> 3), sc4 = (t & 7) * 4;
    const int g0 = rowBase + sr0, g1 = rowBase + sr1;

    float4 p0 = make_float4(0.f, 0.f, 0.f, 0.f), p1 = p0;
    if (g0 < NN) p0 = *(const float4*)&A[(size_t)g0 * K + sc4];
    if (g1 < NN) p1 = *(const float4*)&A[(size_t)g1 * K + sc4];

    f32x4 acc[4][2] = {};

    for (int ks = 0; ks < KS; ++ks) {
        const int b = ks & 1;
        *(float4*)&At[b][sr0][sc4] = p0;
        *(float4*)&At[b][sr1][sc4] = p1;
        __syncthreads();
        if (ks + 1 < KS) {
            p0 = make_float4(0.f, 0.f, 0.f, 0.f); p1 = p0;
            if (g0 < NN) p0 = *(const float4*)&A[(size_t)g0 * K + (ks + 1) * 32 + sc4];
            if (g1 < NN) p1 = *(const float4*)&A[(size_t)g1 * K + (ks + 1) * 32 + sc4];
        }
        f16x8 bf0 = ((const f16x8*)wf)[(ks * 8 + nt0) * 64 + lane];
        f16x8 bf1 = ((const f16x8*)wf)[(ks * 8 + nt0 + 1) * 64 + lane];
#pragma unroll
        for (int mt = 0; mt < 4; ++mt) {
            int row = mt * 16 + (lane & 15);
            float4 a0 = *(const float4*)&At[b][row][(lane >> 4) * 8];
            float4 a1 = *(const float4*)&At[b][row][(lane >> 4) * 8 + 4];
            f16x8 af = pack8h(a0, a1);
            acc[mt][0] = __builtin_amdgcn_mfma_f32_16x16x32_f16(af, bf0, acc[mt][0], 0, 0, 0);
            acc[mt][1] = __builtin_amdgcn_mfma_f32_16x16x32_f16(af, bf1, acc[mt][1], 0, 0, 0);
        }
    }

    const int c0 = lane & 15, rq = lane >> 4;
    float bb0 = EPI ? bias[nt0 * 16 + c0] : 0.f;
    float bb1 = EPI ? bias[nt0 * 16 + 16 + c0] : 0.f;
#pragma unroll
    for (int mt = 0; mt < 4; ++mt) {
#pragma unroll
        for (int reg = 0; reg < 4; ++reg) {
            int grow = rowBase + mt * 16 + rq * 4 + reg;
            if (grow < NN) {
                float v0 = acc[mt][0][reg], v1 = acc[mt][1][reg];
                if (EPI) {
                    float m = mask[grow];
                    v0 = fmaxf(v0 + bb0, 0.f) * m;
                    v1 = fmaxf(v1 + bb1, 0.f) * m;
                }
                if (ROWSCALE) {
                    float rs = rscale[grow];
                    v0 *= rs;
                    v1 *= rs;
                }
                out[(size_t)grow * ostride + ooff + nt0 * 16 + c0] = f2h(v0);
                out[(size_t)grow * ostride + ooff + nt0 * 16 + 16 + c0] = f2h(v1);
            }
        }
    }
}

// ---------------- MFMA matmul (f16 A, K=128), double-buffered, row-scaled out ----------------
__global__ __launch_bounds__(256) void feat_mfma_f16a_kernel(const ushort* __restrict__ A,
                                                             const ushort* __restrict__ wf,
                                                             const float* __restrict__ rscale,
                                                             ushort* __restrict__ out) {
    __shared__ ushort At[2][64][40];
    const int t = threadIdx.x;
    const int w = t >> 6, lane = t & 63;
    const int rowBase = blockIdx.x * 64;
    const int nt0 = w * 2;

    const int sr = t >> 2, sc = (t & 3) * 8;
    const int g = rowBase + sr;

    uint4 p = make_uint4(0, 0, 0, 0);
    if (g < NN) p = *(const uint4*)&A[(size_t)g * HD + sc];

    f32x4 acc[4][2] = {};

    for (int ks = 0; ks < 4; ++ks) {
        const int b = ks & 1;
        *(uint4*)&At[b][sr][sc] = p;
        __syncthreads();
        if (ks + 1 < 4) {
            p = make_uint4(0, 0, 0, 0);
            if (g < NN) p = *(const uint4*)&A[(size_t)g * HD + (ks + 1) * 32 + sc];
        }
        f16x8 bf0 = ((const f16x8*)wf)[(ks * 8 + nt0) * 64 + lane];
        f16x8 bf1 = ((const f16x8*)wf)[(ks * 8 + nt0 + 1) * 64 + lane];
#pragma unroll
        for (int mt = 0; mt < 4; ++mt) {
            int row = mt * 16 + (lane & 15);
            f16x8 af = *(const f16x8*)&At[b][row][(lane >> 4) * 8];
            acc[mt][0] = __builtin_amdgcn_mfma_f32_16x16x32_f16(af, bf0, acc[mt][0], 0, 0, 0);
            acc[mt][1] = __builtin_amdgcn_mfma_f32_16x16x32_f16(af, bf1, acc[mt][1], 0, 0, 0);
        }
    }

    const int c0 = lane & 15, rq = lane >> 4;
#pragma unroll
    for (int mt = 0; mt < 4; ++mt) {
#pragma unroll
        for (int reg = 0; reg < 4; ++reg) {
            int grow = rowBase + mt * 16 + rq * 4 + reg;
            if (grow < NN) {
                float rs = rscale[grow];
                out[(size_t)grow * HD + nt0 * 16 + c0] = f2h(acc[mt][0][reg] * rs);
                out[(size_t)grow * HD + nt0 * 16 + 16 + c0] = f2h(acc[mt][1][reg] * rs);
            }
        }
    }
}

// ---------------- CSR pull aggregation (h pre-scaled by dinv[src]): 2 rows/wave ----------------
__global__ __launch_bounds__(256) void gather_kernel(const int* __restrict__ off,
                                                     const int* __restrict__ cnt,
                                                     const int* __restrict__ csr_idx,
                                                     const float* __restrict__ dinv,
                                                     const ushort* __restrict__ h,
                                                     const float* __restrict__ bias,
                                                     ushort* __restrict__ zb,
                                                     int ostride) {
    int v = blockIdx.x * 4 + (threadIdx.x >> 6);
    if (v >= NN) return;
    const int lane = threadIdx.x & 63;
    const int half = lane >> 5, sl = lane & 31;
    const int s = off[v];
    const int e = s + cnt[v];
    float4 acc = make_float4(0.f, 0.f, 0.f, 0.f);
    int b = s;
    for (; b + 7 < e; b += 8) {
        int i0 = b + half, i1 = b + 2 + half, i2 = b + 4 + half, i3 = b + 6 + half;
        int r0 = csr_idx[i0], r1 = csr_idx[i1], r2 = csr_idx[i2], r3 = csr_idx[i3];
        uint2 u0 = *(const uint2*)&h[(size_t)r0 * HD + sl * 4];
        uint2 u1 = *(const uint2*)&h[(size_t)r1 * HD + sl * 4];
        uint2 u2 = *(const uint2*)&h[(size_t)r2 * HD + sl * 4];
        uint2 u3 = *(const uint2*)&h[(size_t)r3 * HD + sl * 4];
        float2 a0 = h2f2(u0.x), c0 = h2f2(u0.y);
        float2 a1 = h2f2(u1.x), c1 = h2f2(u1.y);
        float2 a2 = h2f2(u2.x), c2 = h2f2(u2.y);
        float2 a3 = h2f2(u3.x), c3 = h2f2(u3.y);
        acc.x += a0.x + a1.x + a2.x + a3.x;
        acc.y += a0.y + a1.y + a2.y + a3.y;
        acc.z += c0.x + c1.x + c2.x + c3.x;
        acc.w += c0.y + c1.y + c2.y + c3.y;
    }
    for (; b < e; b += 2) {
        int i = b + half;
        if (i < e) {
            int r = csr_idx[i];
            uint2 u = *(const uint2*)&h[(size_t)r * HD + sl * 4];
            float2 a = h2f2(u.x), c = h2f2(u.y);
            acc.x += a.x; acc.y += a.y;
            acc.z += c.x; acc.w += c.y;
        }
    }
    acc.x += __shfl_xor(acc.x, 32);
    acc.y += __shfl_xor(acc.y, 32);
    acc.z += __shfl_xor(acc.z, 32);
    acc.w += __shfl_xor(acc.w, 32);
    if (half == 0) {
        float dv = dinv[v];
        float4 bb = *(const float4*)&bias[sl * 4];
        float o0 = fmaxf(fmaf(acc.x, dv, bb.x), 0.f);
        float o1 = fmaxf(fmaf(acc.y, dv, bb.y), 0.f);
        float o2 = fmaxf(fmaf(acc.z, dv, bb.z), 0.f);
        float o3 = fmaxf(fmaf(acc.w, dv, bb.w), 0.f);
        uint2 pk;
        pk.x = pk2h(o0, o1);
        pk.y = pk2h(o2, o3);
        *(uint2*)&zb[(size_t)v * ostride + sl * 4] = pk;
    }
}

// ---------------- decoder: 32-edge blocks, 16KB LDS, 8 blocks/CU ----------------
// wave w covers nt pair (2w, 2w+1) for both 16-edge M-tiles.
__global__ __launch_bounds__(256, 8) void decode_mfma_kernel(const uint2* __restrict__ sedges,
                                                             const int* __restrict__ soidx,
                                                             const ushort* __restrict__ feat,
                                                             const ushort* __restrict__ w1f,
                                                             const float* __restrict__ b1,
                                                             const float* __restrict__ w2,
                                                             const float* __restrict__ b2,
                                                             float* __restrict__ out) {
    __shared__ ushort Flds[8 * 2 * 64 * 8];  // 16 KB; reused for epilogue partials
    const int t = threadIdx.x;
    const int w = t >> 6, lane = t & 63;

    // bijective XCD-chunked swizzle (m204)
    const int nwg = gridDim.x;
    const int orig = blockIdx.x;
    const int q = nwg >> 3, r = nwg & 7;
    const int xcd = orig & 7, k = orig >> 3;
    const int wgid = (xcd < r ? xcd * (q + 1) : r * (q + 1) + (xcd - r) * q) + k;
    const int ebase = wgid * 32;

    const int seg = t & 31, eslot = t >> 5;

    uint2 sdv[4];
#pragma unroll
    for (int j = 0; j < 4; ++j) sdv[j] = sedges[ebase + j * 8 + eslot];
    __builtin_amdgcn_sched_barrier(0);
    uint4 av[4], bv[4];
#pragma unroll
    for (int j = 0; j < 4; ++j) {
        av[j] = *(const uint4*)&feat[(size_t)sdv[j].x * FSTR + seg * 8];
        bv[j] = *(const uint4*)&feat[(size_t)sdv[j].y * FSTR + seg * 8];
    }
    __builtin_amdgcn_sched_barrier(0);
#pragma unroll
    for (int j = 0; j < 4; ++j) {
        int e = j * 8 + eslot;  // 0..31
        uint4 res;
        res.x = h2mul(av[j].x, bv[j].x);
        res.y = h2mul(av[j].y, bv[j].y);
        res.z = h2mul(av[j].z, bv[j].z);
        res.w = h2mul(av[j].w, bv[j].w);
        int ks = seg >> 2;
        int mt = e >> 4;
        int fl = (e & 15) | ((seg & 3) << 4);
        int swz = (seg & 3) | ((ks & 1) << 2);
        ((uint4*)Flds)[(ks * 2 + mt) * 64 + (fl ^ swz)] = res;
    }
    __syncthreads();

    f32x4 acc[2][2] = {};
    const int nt0 = w * 2;
#pragma unroll
    for (int ks = 0; ks < 8; ++ks) {
        f16x8 bf0 = ((const f16x8*)w1f)[(ks * 8 + nt0) * 64 + lane];
        f16x8 bf1 = ((const f16x8*)w1f)[(ks * 8 + nt0 + 1) * 64 + lane];
        const int rswz = ((lane >> 4) & 3) | ((ks & 1) << 2);
#pragma unroll
        for (int mt = 0; mt < 2; ++mt) {
            f16x8 af = ((const f16x8*)Flds)[(ks * 2 + mt) * 64 + (lane ^ rswz)];
            acc[mt][0] = __builtin_amdgcn_mfma_f32_16x16x32_f16(af, bf0, acc[mt][0], 0, 0, 0);
            acc[mt][1] = __builtin_amdgcn_mfma_f32_16x16x32_f16(af, bf1, acc[mt][1], 0, 0, 0);
        }
    }
    __syncthreads();  // Flds reads done; reuse as partials

    float* partf = (float*)Flds;  // [4][32]
    const int c0 = lane & 15, rq = lane >> 4;
    float b1v0 = b1[nt0 * 16 + c0], b1v1 = b1[nt0 * 16 + 16 + c0];
    float w2v0 = w2[nt0 * 16 + c0], w2v1 = w2[nt0 * 16 + 16 + c0];
#pragma unroll
    for (int mt = 0; mt < 2; ++mt) {
#pragma unroll
        for (int reg = 0; reg < 4; ++reg) {
            float h0 = fmaxf(acc[mt][0][reg] + b1v0, 0.f);
            float h1 = fmaxf(acc[mt][1][reg] + b1v1, 0.f);
            float p = fmaf(h0, w2v0, h1 * w2v1);
            p += __shfl_xor(p, 1);
            p += __shfl_xor(p, 2);
            p += __shfl_xor(p, 4);
            p += __shfl_xor(p, 8);
            if (c0 == 0) partf[w * 32 + mt * 16 + rq * 4 + reg] = p;
        }
    }
    __syncthreads();
    if (t < 32) {
        out[soidx[ebase + t]] = partf[t] + partf[32 + t] + partf[64 + t] + partf[96 + t] + b2[0];
    }
}

extern "C" void kernel_launch(void* const* d_in, const int* in_sizes, int n_in,
                              void* d_out, int out_size, void* d_ws, size_t ws_size,
                              hipStream_t stream) {
    const int* edge_index = (const int*)d_in[0];
    const float* chemistry = (const float*)d_in[1];
    const int* pos_edge = (const int*)d_in[2];
    const int* neg_edge = (const int*)d_in[3];
    const float* smiles_mask = (const float*)d_in[4];
    const float* node_emb = (const float*)d_in[5];
    const float* conv_w = (const float*)d_in[6];
    const float* conv_b = (const float*)d_in[7];
    const float* chem_w = (const float*)d_in[8];
    const float* chem_b = (const float*)d_in[9];
    const float* dec_w1 = (const float*)d_in[10];
    const float* dec_b1 = (const float*)d_in[11];
    const float* dec_w2 = (const float*)d_in[12];
    const float* dec_b2 = (const float*)d_in[13];
    float* out = (float*)d_out;

    char* ws = (char*)d_ws;
    int* cnt = (int*)(ws + 0);               // 200000 B
    int* bcnt = (int*)(ws + 204800);         // 784 B (memset covers [0, 205824))
    float* dinv = (float*)(ws + 208896);
    int* partial = (int*)(ws + 409600);
    int* off = (int*)(ws + 614400);
    int* cursor = (int*)(ws + 819200);
    int* bsum = (int*)(ws + 1024000);
    int* bbase = (int*)(ws + 1026048);
    int* csr_idx = (int*)(ws + 1048576);     // 4 MB
    ushort* bufZh = (ushort*)(ws + 9437184); // 12.8 MB (f16 z, layer-0 out)
    int* bh = (int*)(ws + 22237184);         // 307 KB
    int* obh = (int*)(ws + 22657184);        // 307 KB
    ushort* hb = (ushort*)(ws + 35037184);   // 12.8 MB (h; reused for sorted edges)
    ushort* feat = (ushort*)(ws + 47837184); // 25.6 MB  [z | c] interleaved
    ushort* w1f = (ushort*)(ws + 73437184);  // 64 KB
    ushort* wcf = (ushort*)(ws + 73502720);  // 192 KB
    ushort* wc0f = (ushort*)(ws + 73699328); // 32 KB
    ushort* wc1f = (ushort*)(ws + 73732096); // 32 KB
    uint2* sort_sd = (uint2*)(ws + 35037184);   // 6.4 MB (hb region, after gather1)
    int* sort_oidx = (int*)(ws + 41437184);     // 3.2 MB

    const int* e_row = edge_index;
    const int* e_col = edge_index + NE;

    // ---- CSR build + weight fragment pack ----
    hipMemsetAsync(ws, 0, 205824, stream);  // cnt + bcnt
    count_kernel<<<(NE + 255) / 256, 256, 0, stream>>>(e_col, cnt);
    scan1_kernel<<<NB_SCAN, 256, 0, stream>>>(cnt, partial, bsum, dinv);
    scan2_kernel<<<1, 256, 0, stream>>>(bsum);
    scan3_kernel<<<NB_SCAN, 256, 0, stream>>>(partial, bsum, off, cursor);
    fill_kernel<<<(NE + 255) / 256, 256, 0, stream>>>(e_row, e_col, cursor, csr_idx);
    wfrag_all_kernel<<<80, 256, 0, stream>>>(dec_w1, chem_w, conv_w, conv_w + HD * HD,
                                             w1f, wcf, wc0f, wc1f);

    const int mmGrid = (NN + 63) / 64;
    const int gaGrid = (NN + 3) / 4;

    // layer 0: h' = (node_emb @ W0) * dinv[row]  (MFMA), aggregate -> f16 z (bufZh)
    feat_mfma_kernel<4, false, true><<<mmGrid, 256, 0, stream>>>(node_emb, wc0f, nullptr, nullptr, dinv, hb, HD, 0);
    gather_kernel<<<gaGrid, 256, 0, stream>>>(off, cnt, csr_idx, dinv, hb, conv_b, bufZh, HD);

    // layer 1: h' = (z @ W1) * dinv[row]  (f16-A MFMA), aggregate -> f16 z into feat[:,0:128]
    feat_mfma_f16a_kernel<<<mmGrid, 256, 0, stream>>>(bufZh, wc1f, dinv, hb);
    gather_kernel<<<gaGrid, 256, 0, stream>>>(off, cnt, csr_idx, dinv, hb, conv_b + HD, feat, FSTR);

    // ---- edge sort (scratch in freed regions; hb dead after gather1) ----
    ehist_kernel<<<NPB, 256, 0, stream>>>(pos_edge, neg_edge, bh, bcnt);
    escan_kernel<<<1, 256, 0, stream>>>(bcnt, bbase);
    bscan_kernel<<<NBKT, 256, 0, stream>>>(bh, obh);
    epermute_kernel<<<NPB, 256, 0, stream>>>(pos_edge, neg_edge, bbase, obh, sort_sd, sort_oidx);

    // chemistry features -> feat[:,128:256]
    feat_mfma_kernel<24, true, false><<<mmGrid, 256, 0, stream>>>(chemistry, wcf, chem_b, smiles_mask, nullptr, feat, FSTR, HD);

    // decode (pos+neg together, sorted order, scatter by original index)
    decode_mfma_kernel<<<2 * NEP / 32, 256, 0, stream>>>(sort_sd, sort_oidx, feat, w1f,
                                                         dec_b1, dec_w2, dec_b2, out);
}